// Round 1
// baseline (606.186 us; speedup 1.0000x reference)
//
#include <hip/hip_runtime.h>
#include <hip/hip_cooperative_groups.h>
#include <stdint.h>

namespace cg = cooperative_groups;

// Problem constants
#define BB   16
#define TT   4096
#define DIN  64
#define DOUT 64
#define HH   128
#define LCH  64
#define WARM 32
#define SS   96
#define TAPS 32   // validated: R8's 32-step truncation gave absmax == exact path

// HARD-WON FACTS (rounds 0-9):
//  * d_out = 4,194,304 float32 (16 MB): REAL PART only, flat (b*4096+t)*64+o.
//  * 32-tap history truncation is numerically free (R8 absmax 0.0625 == R6 exact).
//  * R9 rocprof: k_conv 75us, but TOTAL 276us -> ~200us is the 11-launch
//    serialized precompute chain. k_conv Occupancy 10% = 1 wave/SIMD.
//  * This round: ONE cooperative kernel, 6 grid.sync() dependency levels,
//    conv phase at 512 thr/block (8 waves, wave = 64 rows x 32 cols).

typedef __attribute__((ext_vector_type(8))) short short8;   // 8 bf16 (4 VGPR)
typedef __attribute__((ext_vector_type(4))) float f32x4;

// ---------- bf16 pack helpers (RNE) ----------
__device__ __forceinline__ uint32_t f2bf(float f) {
  uint32_t x = __float_as_uint(f);
  return (x + 0x7FFFu + ((x >> 16) & 1u)) >> 16;
}
__device__ __forceinline__ uint32_t pack_bf(float re, float im) {
  return f2bf(re) | (f2bf(im) << 16);
}
__device__ __forceinline__ float bf_re(uint32_t u) { return __uint_as_float(u << 16); }
__device__ __forceinline__ float bf_im(uint32_t u) { return __uint_as_float(u & 0xFFFF0000u); }

// fragment-major index for W: B-operand of mfma_f32_16x16x32_bf16
// lane = (k32>>3)*16 + (o&15), j = k32&7; frag id = d*16 + ks*4 + nt
__device__ __forceinline__ int fragIdx(int d, int o, int part, int kk) {
  const int ks = part * 2 + (kk >> 5);
  const int k32 = kk & 31;
  const int nt = o >> 4;
  const int lane = ((k32 >> 3) << 4) | (o & 15);
  return (((d * 16 + ks * 4 + nt) * 64) + lane) * 8 + (k32 & 7);
}

// ===========================================================================
// Device-function phases for the fused cooperative kernel (512 threads/block).
// All staging loops stride 512; fp32 compute uses tid<256 (same math as the
// verified 256-thread kernels -> bit-identical results).
// ===========================================================================

// dst = A @ A (128x128 complex, fp32). tile 0..63 = 8x8 grid of 16x16.
__device__ __forceinline__ void matsq_dev(
    const float* __restrict__ ar, const float* __restrict__ ai,
    int fromPlanes, const float2* __restrict__ src, float2* __restrict__ dst,
    int tileId, unsigned char* smemraw) {
  float2* band  = (float2*)smemraw;             // 16*128 (16 KB)
  float2* panel = (float2*)(smemraw + 16384);   // 32*128 (32 KB)
  const int tid = threadIdx.x;
  const int ib = tileId >> 3, jb = tileId & 7;
  for (int idx = tid; idx < 16 * HH; idx += 512) {
    const int e = (ib * 16 + (idx >> 7)) * HH + (idx & 127);
    band[idx] = fromPlanes ? make_float2(ar[e], ai[e]) : src[e];
  }
  const int jt = tid & 15, it = (tid >> 4) & 15;
  float sre = 0.f, sim = 0.f;
  for (int kp = 0; kp < 4; ++kp) {
    __syncthreads();
    for (int idx = tid; idx < 32 * HH; idx += 512) {
      const int e = (kp * 32 + (idx >> 7)) * HH + (idx & 127);
      panel[idx] = fromPlanes ? make_float2(ar[e], ai[e]) : src[e];
    }
    __syncthreads();
    if (tid < 256) {
#pragma unroll 4
      for (int kk = 0; kk < 32; ++kk) {
        const float2 a = band[it * HH + kp * 32 + kk];
        const float2 bv = panel[kk * HH + jb * 16 + jt];
        sre = fmaf(a.x, bv.x, sre); sre = fmaf(-a.y, bv.y, sre);
        sim = fmaf(a.x, bv.y, sim); sim = fmaf(a.y, bv.x, sim);
      }
    }
  }
  if (tid < 256)
    dst[(ib * 16 + it) * HH + jb * 16 + jt] = make_float2(sre, sim);
}

// dst(128x64) = A(128x128) @ src(128x64), complex fp32. tile 0..7 = 16 rows.
// A from planes (aPlanes) or Aflat; src from planes (sPlanes) or float2.
__device__ __forceinline__ void pmul_dev(
    const float* __restrict__ ar, const float* __restrict__ ai, int aPlanes,
    const float2* __restrict__ Aflat,
    const float* __restrict__ sr, const float* __restrict__ si, int sPlanes,
    const float2* __restrict__ src,
    float2* __restrict__ dst, int tile, unsigned char* smemraw) {
  float2* Pl = (float2*)smemraw;   // 8192 float2 (64 KB)
  const int tid = threadIdx.x;
  if (sPlanes) {
    for (int idx = tid; idx < 8192; idx += 512)
      Pl[idx] = make_float2(sr[idx], si[idx]);
  } else {
    const float4* s4 = (const float4*)src;
    float4* d4 = (float4*)Pl;
    for (int idx = tid; idx < 4096; idx += 512) d4[idx] = s4[idx];
  }
  __syncthreads();
  if (tid < 256) {
    const int i = tile * 16 + (tid >> 4);
    const int c0 = (tid & 15) * 4;
    float accr[4] = {0.f, 0.f, 0.f, 0.f}, acim[4] = {0.f, 0.f, 0.f, 0.f};
#pragma unroll 4
    for (int k = 0; k < 128; ++k) {
      const float2 a = aPlanes ? make_float2(ar[i * 128 + k], ai[i * 128 + k])
                               : Aflat[i * 128 + k];
      const float4 p01 = *(const float4*)&Pl[k * 64 + c0];
      const float4 p23 = *(const float4*)&Pl[k * 64 + c0 + 2];
      accr[0] = fmaf(a.x, p01.x, fmaf(-a.y, p01.y, accr[0]));
      acim[0] = fmaf(a.x, p01.y, fmaf(a.y, p01.x, acim[0]));
      accr[1] = fmaf(a.x, p01.z, fmaf(-a.y, p01.w, accr[1]));
      acim[1] = fmaf(a.x, p01.w, fmaf(a.y, p01.z, acim[1]));
      accr[2] = fmaf(a.x, p23.x, fmaf(-a.y, p23.y, accr[2]));
      acim[2] = fmaf(a.x, p23.y, fmaf(a.y, p23.x, acim[2]));
      accr[3] = fmaf(a.x, p23.z, fmaf(-a.y, p23.w, accr[3]));
      acim[3] = fmaf(a.x, p23.w, fmaf(a.y, p23.z, acim[3]));
    }
#pragma unroll
    for (int cc = 0; cc < 4; ++cc)
      dst[i * 64 + c0 + cc] = make_float2(accr[cc], acim[cc]);
  }
}

// V_d = i^d * Wo * P_d -> fragment-major bf16. tile 0..3 = 16 output rows.
__device__ __forceinline__ void makeV_dev(
    const float2* __restrict__ P,
    const float* __restrict__ wor, const float* __restrict__ woi,
    short* __restrict__ Wf, int d, int tile, unsigned char* smemraw) {
  float2* Pl = (float2*)smemraw;
  const int tid = threadIdx.x;
  const float4* s4 = (const float4*)(P + (size_t)d * 8192);
  float4* d4 = (float4*)Pl;
  for (int idx = tid; idx < 4096; idx += 512) d4[idx] = s4[idx];
  __syncthreads();
  if (tid < 256) {
    const int o = tile * 16 + (tid >> 4);
    const int c0 = (tid & 15) * 4;
    float accr[4] = {0.f, 0.f, 0.f, 0.f}, acim[4] = {0.f, 0.f, 0.f, 0.f};
#pragma unroll 4
    for (int k = 0; k < 128; ++k) {
      const float2 a = make_float2(wor[o * 128 + k], woi[o * 128 + k]);
      const float4 p01 = *(const float4*)&Pl[k * 64 + c0];
      const float4 p23 = *(const float4*)&Pl[k * 64 + c0 + 2];
      accr[0] = fmaf(a.x, p01.x, fmaf(-a.y, p01.y, accr[0]));
      acim[0] = fmaf(a.x, p01.y, fmaf(a.y, p01.x, acim[0]));
      accr[1] = fmaf(a.x, p01.z, fmaf(-a.y, p01.w, accr[1]));
      acim[1] = fmaf(a.x, p01.w, fmaf(a.y, p01.z, acim[1]));
      accr[2] = fmaf(a.x, p23.x, fmaf(-a.y, p23.y, accr[2]));
      acim[2] = fmaf(a.x, p23.y, fmaf(a.y, p23.x, acim[2]));
      accr[3] = fmaf(a.x, p23.z, fmaf(-a.y, p23.w, accr[3]));
      acim[3] = fmaf(a.x, p23.w, fmaf(a.y, p23.z, acim[3]));
    }
#pragma unroll
    for (int cc = 0; cc < 4; ++cc) {
      const float re = accr[cc], im = acim[cc];
      float tr, ti;
      switch (d & 3) {                 // multiply by i^d
        case 0: tr = re;  ti = im;  break;
        case 1: tr = -im; ti = re;  break;
        case 2: tr = -re; ti = -im; break;
        default: tr = im; ti = -re; break;
      }
      const int kk = c0 + cc;
      Wf[fragIdx(d, o, 0, kk)] = (short)f2bf(tr);    // Re(V)  (x_re column)
      Wf[fragIdx(d, o, 1, kk)] = (short)f2bf(-ti);   // -Im(V) (x_im column)
    }
  }
}

// The conv GEMM phase. 256 blocks x 512 thr. Block: b = blk&15, 256-row tile.
// 8 waves: wr = w>>1 owns rows wr*64..+63, nh = w&1 owns out cols nh*32..+31.
// mi=4, nt=2: same B-operand L2 traffic/CU as R9, but 2 waves/SIMD.
__device__ __forceinline__ void conv_dev(
    const float* __restrict__ xr, const float* __restrict__ xi,
    const short* __restrict__ Wf, float* __restrict__ out,
    unsigned char* smemraw) {
  short* xs = (short*)smemraw;   // [288][136] bf16: [re(64)|im(64)|pad8]
  const int tid = threadIdx.x;
  const int blk = blockIdx.x;
  const int b = blk & 15;
  const int t0 = (blk >> 4) * 256;

  // stage x tile (fp32 -> bf16)
  for (int idx = tid; idx < 288 * 16; idx += 512) {
    const int r = idx >> 4;
    const int kq = (idx & 15) << 2;
    const int t = t0 + r - 32;
    uint32_t r01 = 0u, r23 = 0u, i01 = 0u, i23 = 0u;
    if (t >= 0) {
      const size_t g = ((size_t)b * TT + t) * 64 + kq;
      const float4 vr = *(const float4*)(xr + g);
      const float4 vi = *(const float4*)(xi + g);
      r01 = f2bf(vr.x) | (f2bf(vr.y) << 16);
      r23 = f2bf(vr.z) | (f2bf(vr.w) << 16);
      i01 = f2bf(vi.x) | (f2bf(vi.y) << 16);
      i23 = f2bf(vi.z) | (f2bf(vi.w) << 16);
    }
    *(uint2*)&xs[r * 136 + kq]      = make_uint2(r01, r23);
    *(uint2*)&xs[r * 136 + 64 + kq] = make_uint2(i01, i23);
  }
  __syncthreads();

  const int w = tid >> 6;
  const int lane = tid & 63;
  const int wr = w >> 1;        // row group 0..3
  const int nh = w & 1;         // col half 0..1
  const int lm = lane & 15;
  const int kc8 = (lane >> 4) << 3;
  f32x4 acc[4][2];
#pragma unroll
  for (int mi = 0; mi < 4; ++mi)
#pragma unroll
    for (int n = 0; n < 2; ++n) acc[mi][n] = (f32x4){0.f, 0.f, 0.f, 0.f};

#pragma unroll 1
  for (int d = 0; d < TAPS; ++d) {
    const int rb = 32 - d + wr * 64 + lm;
#pragma unroll
    for (int ks = 0; ks < 4; ++ks) {
      const int col = (ks >> 1) * 64 + (ks & 1) * 32 + kc8;
      short8 bq[2];
#pragma unroll
      for (int n = 0; n < 2; ++n)
        bq[n] = *(const short8*)(Wf +
            (((d * 16 + ks * 4 + nh * 2 + n) * 64 + lane) << 3));
      short8 aq[4];
#pragma unroll
      for (int mi = 0; mi < 4; ++mi)
        aq[mi] = *(const short8*)&xs[(rb + mi * 16) * 136 + col];
#pragma unroll
      for (int mi = 0; mi < 4; ++mi)
#pragma unroll
        for (int n = 0; n < 2; ++n)
          acc[mi][n] = __builtin_amdgcn_mfma_f32_16x16x32_bf16(
              aq[mi], bq[n], acc[mi][n], 0, 0, 0);
    }
  }

  // store: D[m][n]: m = (lane>>4)*4 + reg, n = lane&15  (verified C/D layout)
  const int mrow = wr * 64 + ((lane >> 4) << 2);
#pragma unroll
  for (int mi = 0; mi < 4; ++mi) {
#pragma unroll
    for (int n = 0; n < 2; ++n) {
      const int o = (nh * 2 + n) * 16 + lm;
      float* p = out + ((size_t)b * TT + t0 + mrow + mi * 16) * 64 + o;
#pragma unroll
      for (int rg = 0; rg < 4; ++rg) p[(size_t)rg * 64] = acc[mi][n][rg];
    }
  }
}

// ===========================================================================
// The fused cooperative kernel: 256 blocks x 512 threads, 6 grid syncs.
// Stage plan (dependency depth is exactly 6):
//   S0: Wh^2; P_0=Wi copy; P_1=Wh*Wi      S3: Wh^16; P_8..15
//   S1: Wh^4; P_2..3                      S4: P_16..31; V_0..15
//   S2: Wh^8; P_4..7                      S5: V_16..31
//   S6: conv GEMM (all 256 blocks)
// ===========================================================================
__global__ __launch_bounds__(512, 2) void k_all(
    const float* __restrict__ xr, const float* __restrict__ xi,
    const float* __restrict__ wir, const float* __restrict__ wii,
    const float* __restrict__ whr, const float* __restrict__ whi,
    const float* __restrict__ wor, const float* __restrict__ woi,
    float2* __restrict__ ws, float* __restrict__ out) {
  __shared__ __align__(16) unsigned char smem[78336];
  float2* Wp0 = ws;                   // Wh^2
  float2* Wp1 = Wp0 + 16384;          // Wh^4
  float2* Wp2 = Wp1 + 16384;          // Wh^8
  float2* Wp3 = Wp2 + 16384;          // Wh^16
  float2* P   = Wp3 + 16384;          // P_d, d=0..31 (32 x 8192 float2)
  short*  Wfr = (short*)(P + (size_t)32 * 8192);
  const int blk = blockIdx.x;
  const int tid = threadIdx.x;
  cg::grid_group grid = cg::this_grid();

  // ---- S0: Wh^2 ; P_0 ; P_1 ----  (dummy src ptrs = Wp1: valid, unwritten)
  if (blk < 64) {
    matsq_dev(whr, whi, 1, Wp1, Wp0, blk, smem);
  } else if (blk < 80) {
    const int idx = (blk - 64) * 512 + tid;           // exactly 8192
    P[idx] = make_float2(wir[idx], wii[idx]);
  } else if (blk < 88) {
    pmul_dev(whr, whi, 1, Wp1, wir, wii, 1, Wp1, P + 8192, blk - 80, smem);
  }
  __threadfence(); grid.sync();

  // ---- S1: Wh^4 ; P_2..3 ----
  if (blk < 64) {
    matsq_dev(whr, whi, 0, Wp0, Wp1, blk, smem);
  } else if (blk < 80) {
    const int j = (blk - 64) >> 3;
    pmul_dev(whr, whi, 0, Wp0, wir, wii, 0, P + (size_t)j * 8192,
             P + (size_t)(2 + j) * 8192, (blk - 64) & 7, smem);
  }
  __threadfence(); grid.sync();

  // ---- S2: Wh^8 ; P_4..7 ----
  if (blk < 64) {
    matsq_dev(whr, whi, 0, Wp1, Wp2, blk, smem);
  } else if (blk < 96) {
    const int j = (blk - 64) >> 3;
    pmul_dev(whr, whi, 0, Wp1, wir, wii, 0, P + (size_t)j * 8192,
             P + (size_t)(4 + j) * 8192, (blk - 64) & 7, smem);
  }
  __threadfence(); grid.sync();

  // ---- S3: Wh^16 ; P_8..15 ----
  if (blk < 64) {
    matsq_dev(whr, whi, 0, Wp2, Wp3, blk, smem);
  } else if (blk < 128) {
    const int j = (blk - 64) >> 3;
    pmul_dev(whr, whi, 0, Wp2, wir, wii, 0, P + (size_t)j * 8192,
             P + (size_t)(8 + j) * 8192, (blk - 64) & 7, smem);
  }
  __threadfence(); grid.sync();

  // ---- S4: P_16..31 ; V_0..15 ----
  if (blk < 128) {
    const int j = blk >> 3;
    pmul_dev(whr, whi, 0, Wp3, wir, wii, 0, P + (size_t)j * 8192,
             P + (size_t)(16 + j) * 8192, blk & 7, smem);
  } else if (blk < 192) {
    makeV_dev(P, wor, woi, Wfr, (blk - 128) >> 2, (blk - 128) & 3, smem);
  }
  __threadfence(); grid.sync();

  // ---- S5: V_16..31 ----
  if (blk < 64) {
    makeV_dev(P, wor, woi, Wfr, 16 + (blk >> 2), blk & 3, smem);
  }
  __threadfence(); grid.sync();

  // ---- S6: conv GEMM ----
  conv_dev(xr, xi, Wfr, out, smem);
}

// ===========================================================================
// FALLBACK kernels (proven R9 path): used if cooperative launch is refused
// or ws too small. Verbatim from the 276us version.
// ===========================================================================
__global__ __launch_bounds__(256) void k_matsq(
    const float* __restrict__ ar, const float* __restrict__ ai,
    int fromPlanes, const float2* __restrict__ src, float2* __restrict__ dst) {
  __shared__ float2 band[16 * HH];
  __shared__ float2 panel[32 * HH];
  const int tid = threadIdx.x;
  const int ib = blockIdx.x >> 3, jb = blockIdx.x & 7;
  for (int idx = tid; idx < 16 * HH; idx += 256) {
    const int e = (ib * 16 + (idx >> 7)) * HH + (idx & 127);
    band[idx] = fromPlanes ? make_float2(ar[e], ai[e]) : src[e];
  }
  const int jt = tid & 15, it = tid >> 4;
  float sre = 0.f, sim = 0.f;
  for (int kp = 0; kp < 4; ++kp) {
    __syncthreads();
    for (int idx = tid; idx < 32 * HH; idx += 256) {
      const int e = (kp * 32 + (idx >> 7)) * HH + (idx & 127);
      panel[idx] = fromPlanes ? make_float2(ar[e], ai[e]) : src[e];
    }
    __syncthreads();
#pragma unroll 4
    for (int kk = 0; kk < 32; ++kk) {
      const float2 a = band[it * HH + kp * 32 + kk];
      const float2 bv = panel[kk * HH + jb * 16 + jt];
      sre = fmaf(a.x, bv.x, sre); sre = fmaf(-a.y, bv.y, sre);
      sim = fmaf(a.x, bv.y, sim); sim = fmaf(a.y, bv.x, sim);
    }
  }
  dst[(ib * 16 + it) * HH + jb * 16 + jt] = make_float2(sre, sim);
}

__global__ __launch_bounds__(256) void k_pcopy(
    const float* __restrict__ wir, const float* __restrict__ wii,
    float2* __restrict__ P) {
  const int idx = blockIdx.x * 256 + threadIdx.x;
  P[idx] = make_float2(wir[idx], wii[idx]);
}

__global__ __launch_bounds__(256) void k_pmul(
    const float* __restrict__ ar, const float* __restrict__ ai,
    int fromPlanes, const float2* __restrict__ Aflat,
    float2* __restrict__ P, int cnt) {
  __shared__ float2 Pl[8192];
  const int tid = threadIdx.x;
  const int j = blockIdx.x >> 3;
  const int tile = blockIdx.x & 7;
  const float2* src = P + (size_t)j * 8192;
  float2* dst = P + (size_t)(cnt + j) * 8192;
  {
    const float4* s4 = (const float4*)src;
    float4* d4 = (float4*)Pl;
    for (int idx = tid; idx < 4096; idx += 256) d4[idx] = s4[idx];
  }
  __syncthreads();
  const int i = tile * 16 + (tid >> 4);
  const int c0 = (tid & 15) * 4;
  float accr[4] = {0.f, 0.f, 0.f, 0.f}, acim[4] = {0.f, 0.f, 0.f, 0.f};
#pragma unroll 4
  for (int k = 0; k < 128; ++k) {
    const float2 a = fromPlanes ? make_float2(ar[i * 128 + k], ai[i * 128 + k])
                                : Aflat[i * 128 + k];
    const float4 p01 = *(const float4*)&Pl[k * 64 + c0];
    const float4 p23 = *(const float4*)&Pl[k * 64 + c0 + 2];
    accr[0] = fmaf(a.x, p01.x, fmaf(-a.y, p01.y, accr[0]));
    acim[0] = fmaf(a.x, p01.y, fmaf(a.y, p01.x, acim[0]));
    accr[1] = fmaf(a.x, p01.z, fmaf(-a.y, p01.w, accr[1]));
    acim[1] = fmaf(a.x, p01.w, fmaf(a.y, p01.z, acim[1]));
    accr[2] = fmaf(a.x, p23.x, fmaf(-a.y, p23.y, accr[2]));
    acim[2] = fmaf(a.x, p23.y, fmaf(a.y, p23.x, acim[2]));
    accr[3] = fmaf(a.x, p23.z, fmaf(-a.y, p23.w, accr[3]));
    acim[3] = fmaf(a.x, p23.w, fmaf(a.y, p23.z, acim[3]));
  }
#pragma unroll
  for (int cc = 0; cc < 4; ++cc)
    dst[i * 64 + c0 + cc] = make_float2(accr[cc], acim[cc]);
}

__global__ __launch_bounds__(256) void k_makeV(
    const float2* __restrict__ P,
    const float* __restrict__ wor, const float* __restrict__ woi,
    short* __restrict__ Wf) {
  __shared__ float2 Pl[8192];
  const int tid = threadIdx.x;
  const int d = blockIdx.x >> 2;
  const int tile = blockIdx.x & 3;
  const float2* src = P + (size_t)d * 8192;
  {
    const float4* s4 = (const float4*)src;
    float4* d4 = (float4*)Pl;
    for (int idx = tid; idx < 4096; idx += 256) d4[idx] = s4[idx];
  }
  __syncthreads();
  const int o = tile * 16 + (tid >> 4);
  const int c0 = (tid & 15) * 4;
  float accr[4] = {0.f, 0.f, 0.f, 0.f}, acim[4] = {0.f, 0.f, 0.f, 0.f};
#pragma unroll 4
  for (int k = 0; k < 128; ++k) {
    const float2 a = make_float2(wor[o * 128 + k], woi[o * 128 + k]);
    const float4 p01 = *(const float4*)&Pl[k * 64 + c0];
    const float4 p23 = *(const float4*)&Pl[k * 64 + c0 + 2];
    accr[0] = fmaf(a.x, p01.x, fmaf(-a.y, p01.y, accr[0]));
    acim[0] = fmaf(a.x, p01.y, fmaf(a.y, p01.x, acim[0]));
    accr[1] = fmaf(a.x, p01.z, fmaf(-a.y, p01.w, accr[1]));
    acim[1] = fmaf(a.x, p01.w, fmaf(a.y, p01.z, acim[1]));
    accr[2] = fmaf(a.x, p23.x, fmaf(-a.y, p23.y, accr[2]));
    acim[2] = fmaf(a.x, p23.y, fmaf(a.y, p23.x, acim[2]));
    accr[3] = fmaf(a.x, p23.z, fmaf(-a.y, p23.w, accr[3]));
    acim[3] = fmaf(a.x, p23.w, fmaf(a.y, p23.z, acim[3]));
  }
#pragma unroll
  for (int cc = 0; cc < 4; ++cc) {
    const float re = accr[cc], im = acim[cc];
    float tr, ti;
    switch (d & 3) {
      case 0: tr = re;  ti = im;  break;
      case 1: tr = -im; ti = re;  break;
      case 2: tr = -re; ti = -im; break;
      default: tr = im; ti = -re; break;
    }
    const int kk = c0 + cc;
    Wf[fragIdx(d, o, 0, kk)] = (short)f2bf(tr);
    Wf[fragIdx(d, o, 1, kk)] = (short)f2bf(-ti);
  }
}

__global__ __launch_bounds__(256, 1) void k_conv(
    const float* __restrict__ xr, const float* __restrict__ xi,
    const short* __restrict__ Wf, float* __restrict__ out) {
  __shared__ short xs[288 * 136];
  const int tid = threadIdx.x;
  const int b = blockIdx.x & 15;
  const int t0 = (blockIdx.x >> 4) * 256;
  for (int idx = tid; idx < 288 * 16; idx += 256) {
    const int r = idx >> 4;
    const int kq = (idx & 15) << 2;
    const int t = t0 + r - 32;
    uint32_t r01 = 0u, r23 = 0u, i01 = 0u, i23 = 0u;
    if (t >= 0) {
      const size_t g = ((size_t)b * TT + t) * 64 + kq;
      const float4 vr = *(const float4*)(xr + g);
      const float4 vi = *(const float4*)(xi + g);
      r01 = f2bf(vr.x) | (f2bf(vr.y) << 16);
      r23 = f2bf(vr.z) | (f2bf(vr.w) << 16);
      i01 = f2bf(vi.x) | (f2bf(vi.y) << 16);
      i23 = f2bf(vi.z) | (f2bf(vi.w) << 16);
    }
    *(uint2*)&xs[r * 136 + kq]      = make_uint2(r01, r23);
    *(uint2*)&xs[r * 136 + 64 + kq] = make_uint2(i01, i23);
  }
  __syncthreads();

  const int w = tid >> 6;
  const int lane = tid & 63;
  const int lm = lane & 15;
  const int kc8 = (lane >> 4) << 3;
  f32x4 acc[4][4];
#pragma unroll
  for (int mi = 0; mi < 4; ++mi)
#pragma unroll
    for (int nt = 0; nt < 4; ++nt) acc[mi][nt] = (f32x4){0.f, 0.f, 0.f, 0.f};

#pragma unroll 1
  for (int d = 0; d < TAPS; ++d) {
    const int rb = 32 - d + w * 64 + lm;
#pragma unroll
    for (int ks = 0; ks < 4; ++ks) {
      const int col = (ks >> 1) * 64 + (ks & 1) * 32 + kc8;
      short8 bq[4];
#pragma unroll
      for (int nt = 0; nt < 4; ++nt)
        bq[nt] = *(const short8*)(Wf + (((d * 16 + ks * 4 + nt) * 64 + lane) << 3));
      short8 aq[4];
#pragma unroll
      for (int mi = 0; mi < 4; ++mi)
        aq[mi] = *(const short8*)&xs[(rb + mi * 16) * 136 + col];
#pragma unroll
      for (int mi = 0; mi < 4; ++mi)
#pragma unroll
        for (int nt = 0; nt < 4; ++nt)
          acc[mi][nt] = __builtin_amdgcn_mfma_f32_16x16x32_bf16(
              aq[mi], bq[nt], acc[mi][nt], 0, 0, 0);
    }
  }

  const int mrow = w * 64 + ((lane >> 4) << 2);
#pragma unroll
  for (int mi = 0; mi < 4; ++mi) {
#pragma unroll
    for (int nt = 0; nt < 4; ++nt) {
      const int o = nt * 16 + lm;
      float* p = out + ((size_t)b * TT + t0 + mrow + mi * 16) * 64 + o;
#pragma unroll
      for (int rg = 0; rg < 4; ++rg) p[(size_t)rg * 64] = acc[mi][nt][rg];
    }
  }
}

// ---------------------------------------------------------------------------
// FALLBACK (R8, proven 596 us): single fused truncated-scan kernel.
// ---------------------------------------------------------------------------
__global__ __launch_bounds__(256) void k_fused(
    const float* __restrict__ xr, const float* __restrict__ xi,
    const float* __restrict__ wir, const float* __restrict__ wii,
    const float* __restrict__ whr, const float* __restrict__ whi,
    const float* __restrict__ wor, const float* __restrict__ woi,
    float* __restrict__ out) {
  __shared__ __align__(16) unsigned char smem[63488];
  uint32_t* xpl  = (uint32_t*)smem;
  uint32_t* wiq  = (uint32_t*)(smem + 49152);
  uint32_t* xtq  = (uint32_t*)(smem + 57344);
  float2*   part = (float2*)(smem + 49152);
  float2*   hbuf = (float2*)(smem + 59392);
  uint32_t* woA  = (uint32_t*)smem;
  const int tid = threadIdx.x;
  const int c = blockIdx.x >> 4;
  const int b = blockIdx.x & 15;
  const int t0 = c * LCH - WARM;

  const int ho = tid & 31;
  const int tg = tid >> 5;
  float accr[4][12], acci[4][12];
#pragma unroll
  for (int a = 0; a < 4; ++a)
#pragma unroll
    for (int t = 0; t < 12; ++t) { accr[a][t] = 0.f; acci[a][t] = 0.f; }

#pragma unroll 1
  for (int q = 0; q < 4; ++q) {
    if (q) __syncthreads();
    for (int idx = tid; idx < 16 * HH; idx += 256) {
      const int dd = idx & 15, h = idx >> 4;
      const int g = h * DIN + q * 16 + dd;
      wiq[dd * 128 + h] = pack_bf(wir[g], wii[g]);
    }
    for (int idx = tid; idx < 16 * SS; idx += 256) {
      const int dd = idx & 15, s = idx >> 4;
      const int t = t0 + s;
      uint32_t v = 0u;
      if (t >= 0) {
        const size_t g = ((size_t)b * TT + t) * DIN + q * 16 + dd;
        v = pack_bf(xr[g], xi[g]);
      }
      xtq[dd * 96 + s] = v;
    }
    __syncthreads();
#pragma unroll 4
    for (int dd = 0; dd < 16; ++dd) {
      const uint4 wv  = *(const uint4*)&wiq[dd * 128 + ho * 4];
      const uint4 xv0 = *(const uint4*)&xtq[dd * 96 + tg * 12];
      const uint4 xv1 = *(const uint4*)&xtq[dd * 96 + tg * 12 + 4];
      const uint4 xv2 = *(const uint4*)&xtq[dd * 96 + tg * 12 + 8];
      float wre[4], wim[4], xre[12], xim[12];
      wre[0] = bf_re(wv.x); wim[0] = bf_im(wv.x);
      wre[1] = bf_re(wv.y); wim[1] = bf_im(wv.y);
      wre[2] = bf_re(wv.z); wim[2] = bf_im(wv.z);
      wre[3] = bf_re(wv.w); wim[3] = bf_im(wv.w);
      xre[0] = bf_re(xv0.x); xim[0] = bf_im(xv0.x);
      xre[1] = bf_re(xv0.y); xim[1] = bf_im(xv0.y);
      xre[2] = bf_re(xv0.z); xim[2] = bf_im(xv0.z);
      xre[3] = bf_re(xv0.w); xim[3] = bf_im(xv0.w);
      xre[4] = bf_re(xv1.x); xim[4] = bf_im(xv1.x);
      xre[5] = bf_re(xv1.y); xim[5] = bf_im(xv1.y);
      xre[6] = bf_re(xv1.z); xim[6] = bf_im(xv1.z);
      xre[7] = bf_re(xv1.w); xim[7] = bf_im(xv1.w);
      xre[8] = bf_re(xv2.x); xim[8] = bf_im(xv2.x);
      xre[9] = bf_re(xv2.y); xim[9] = bf_im(xv2.y);
      xre[10] = bf_re(xv2.z); xim[10] = bf_im(xv2.z);
      xre[11] = bf_re(xv2.w); xim[11] = bf_im(xv2.w);
#pragma unroll
      for (int a = 0; a < 4; ++a)
#pragma unroll
        for (int t = 0; t < 12; ++t) {
          accr[a][t] = fmaf(wre[a], xre[t], accr[a][t]);
          accr[a][t] = fmaf(-wim[a], xim[t], accr[a][t]);
          acci[a][t] = fmaf(wre[a], xim[t], acci[a][t]);
          acci[a][t] = fmaf(wim[a], xre[t], acci[a][t]);
        }
    }
  }
  __syncthreads();

#pragma unroll
  for (int tt = 0; tt < 12; ++tt) {
    uint4 v;
    v.x = pack_bf(accr[0][tt], acci[0][tt]);
    v.y = pack_bf(accr[1][tt], acci[1][tt]);
    v.z = pack_bf(accr[2][tt], acci[2][tt]);
    v.w = pack_bf(accr[3][tt], acci[3][tt]);
    *(uint4*)&xpl[(tg * 12 + tt) * 128 + ho * 4] = v;
  }
  if (tid < HH) hbuf[tid] = make_float2(0.f, 0.f);

  const int p8 = tid & 7;
  const int jg = tid >> 3;
  float wr[4][16], wim_[4][16];
#pragma unroll
  for (int a = 0; a < 4; ++a)
#pragma unroll
    for (int i = 0; i < 16; i += 4) {
      const float4 vr = *(const float4*)(whr + (size_t)(jg * 4 + a) * HH + p8 * 16 + i);
      wr[a][i] = vr.x; wr[a][i + 1] = vr.y; wr[a][i + 2] = vr.z; wr[a][i + 3] = vr.w;
      const float4 vi = *(const float4*)(whi + (size_t)(jg * 4 + a) * HH + p8 * 16 + i);
      wim_[a][i] = vi.x; wim_[a][i + 1] = vi.y; wim_[a][i + 2] = vi.z; wim_[a][i + 3] = vi.w;
    }
  __syncthreads();

#pragma unroll 1
  for (int s = 0; s < SS; ++s) {
    const uint32_t u = (tid < HH) ? xpl[s * 128 + tid] : 0u;
    float sre[4] = {0.f, 0.f, 0.f, 0.f}, sim[4] = {0.f, 0.f, 0.f, 0.f};
#pragma unroll
    for (int i = 0; i < 16; ++i) {
      const float2 hv = hbuf[i * 8 + p8];
#pragma unroll
      for (int a = 0; a < 4; ++a) {
        sre[a] = fmaf(wr[a][i], hv.x, sre[a]);
        sre[a] = fmaf(-wim_[a][i], hv.y, sre[a]);
        sim[a] = fmaf(wr[a][i], hv.y, sim[a]);
        sim[a] = fmaf(wim_[a][i], hv.x, sim[a]);
      }
    }
#pragma unroll
    for (int a = 0; a < 4; ++a)
      part[(jg * 4 + a) * 10 + p8] = make_float2(sre[a], sim[a]);
    __syncthreads();
    if (tid < HH) {
      const int j = tid;
      const float4 q0 = *(const float4*)&part[j * 10];
      const float4 q1 = *(const float4*)&part[j * 10 + 2];
      const float4 q2 = *(const float4*)&part[j * 10 + 4];
      const float4 q3 = *(const float4*)&part[j * 10 + 6];
      const float R = ((q0.x + q0.z) + (q1.x + q1.z)) + ((q2.x + q2.z) + (q3.x + q3.z));
      const float I = ((q0.y + q0.w) + (q1.y + q1.w)) + ((q2.y + q2.w) + (q3.y + q3.w));
      const float hr = bf_re(u) - I;
      const float hi = bf_im(u) + R;
      hbuf[(j & 15) * 8 + (j >> 4)] = make_float2(hr, hi);
      if (s >= WARM) xpl[s * 128 + j] = pack_bf(hr, hi);
    }
    __syncthreads();
  }

  const int og = tid & 15;
  const int tg2 = tid >> 4;
  float orr[4][4];
#pragma unroll
  for (int a = 0; a < 4; ++a)
#pragma unroll
    for (int t = 0; t < 4; ++t) orr[a][t] = 0.f;
#pragma unroll 1
  for (int kp = 0; kp < 2; ++kp) {
    __syncthreads();
    for (int idx = tid; idx < DOUT * 64; idx += 256) {
      const int o = idx >> 6, hh = idx & 63;
      woA[hh * 64 + o] = pack_bf(wor[(size_t)o * HH + kp * 64 + hh],
                                 woi[(size_t)o * HH + kp * 64 + hh]);
    }
    __syncthreads();
    for (int hh = 0; hh < 64; ++hh) {
      const uint4 wv = *(const uint4*)&woA[hh * 64 + og * 4];
      float wre[4], wimv[4];
      wre[0] = bf_re(wv.x); wimv[0] = bf_im(wv.x);
      wre[1] = bf_re(wv.y); wimv[1] = bf_im(wv.y);
      wre[2] = bf_re(wv.z); wimv[2] = bf_im(wv.z);
      wre[3] = bf_re(wv.w); wimv[3] = bf_im(wv.w);
#pragma unroll
      for (int tt = 0; tt < 4; ++tt) {
        const uint32_t hu = xpl[(WARM + tg2 * 4 + tt) * 128 + kp * 64 + hh];
        const float hre = bf_re(hu), him = bf_im(hu);
#pragma unroll
        for (int a = 0; a < 4; ++a) {
          orr[a][tt] = fmaf(wre[a], hre, orr[a][tt]);
          orr[a][tt] = fmaf(-wimv[a], him, orr[a][tt]);
        }
      }
    }
  }
#pragma unroll
  for (int tt = 0; tt < 4; ++tt) {
    float* po = out + ((size_t)b * TT + (size_t)c * LCH + tg2 * 4 + tt) * DOUT + og * 4;
    *(float4*)po = make_float4(orr[0][tt], orr[1][tt], orr[2][tt], orr[3][tt]);
  }
}

// ---------------------------------------------------------------------------
extern "C" void kernel_launch(void* const* d_in, const int* in_sizes, int n_in,
                              void* d_out, int out_size, void* d_ws, size_t ws_size,
                              hipStream_t stream) {
  const float* xr  = (const float*)d_in[0];
  const float* xi  = (const float*)d_in[1];
  const float* wir = (const float*)d_in[2];
  const float* wii = (const float*)d_in[3];
  const float* whr = (const float*)d_in[4];
  const float* whi = (const float*)d_in[5];
  const float* wor = (const float*)d_in[6];
  const float* woi = (const float*)d_in[7];
  float* out = (float*)d_out;
  (void)in_sizes; (void)n_in; (void)out_size;

  const size_t NEED = 3145728;   // 3 MB: Wh powers 512K + P 2M + W_frag 512K
  if (ws_size >= NEED) {
    float2* ws = (float2*)d_ws;
    void* args[10] = { (void*)&xr, (void*)&xi, (void*)&wir, (void*)&wii,
                       (void*)&whr, (void*)&whi, (void*)&wor, (void*)&woi,
                       (void*)&ws, (void*)&out };
    const hipError_t cerr = hipLaunchCooperativeKernel(
        reinterpret_cast<void*>(k_all), dim3(256), dim3(512), args, 0u, stream);
    if (cerr == hipSuccess) return;

    // Cooperative refused -> proven R9 multi-kernel chain.
    float2* Wp0 = (float2*)d_ws;
    float2* Wp1 = Wp0 + 16384;
    float2* Wp2 = Wp1 + 16384;
    float2* Wp3 = Wp2 + 16384;
    float2* P   = Wp3 + 16384;
    short*  Wfr = (short*)(P + (size_t)32 * 8192);

    k_matsq<<<64, 256, 0, stream>>>(whr, whi, 1, Wp1, Wp0);   // Wh^2
    k_matsq<<<64, 256, 0, stream>>>(whr, whi, 0, Wp0, Wp1);   // Wh^4
    k_matsq<<<64, 256, 0, stream>>>(whr, whi, 0, Wp1, Wp2);   // Wh^8
    k_matsq<<<64, 256, 0, stream>>>(whr, whi, 0, Wp2, Wp3);   // Wh^16

    k_pcopy<<<32, 256, 0, stream>>>(wir, wii, P);             // P_0
    k_pmul<<<8,   256, 0, stream>>>(whr, whi, 1, Wp0, P, 1);  // P_1
    k_pmul<<<16,  256, 0, stream>>>(whr, whi, 0, Wp0, P, 2);  // P_2..3
    k_pmul<<<32,  256, 0, stream>>>(whr, whi, 0, Wp1, P, 4);  // P_4..7
    k_pmul<<<64,  256, 0, stream>>>(whr, whi, 0, Wp2, P, 8);  // P_8..15
    k_pmul<<<128, 256, 0, stream>>>(whr, whi, 0, Wp3, P, 16); // P_16..31

    k_makeV<<<128, 256, 0, stream>>>(P, wor, woi, Wfr);       // V_d -> bf16 frags
    k_conv<<<256, 256, 0, stream>>>(xr, xi, Wfr, out);        // the GEMM
  } else {
    k_fused<<<(TT / LCH) * BB, 256, 0, stream>>>(
        xr, xi, wir, wii, whr, whi, wor, woi, out);
  }
}

// Round 2
// 273.177 us; speedup vs baseline: 2.2190x; 2.2190x over previous
//
#include <hip/hip_runtime.h>
#include <stdint.h>

// Problem constants
#define BB   16
#define TT   4096
#define DIN  64
#define DOUT 64
#define HH   128
#define LCH  64
#define WARM 32
#define SS   96
#define TAPS 32   // validated: R8's 32-step truncation gave absmax == exact path

// HARD-WON FACTS (rounds 0-10):
//  * d_out = 4,194,304 float32 (16 MB): REAL PART only, flat (b*4096+t)*64+o.
//  * 32-tap history truncation is numerically free (absmax 0.0625 == exact).
//  * R9: multi-kernel chain = 276us total; conv 75us, ~200us = 11 dependent
//    launch gaps. R10: cooperative fusion PASSED but 510us — cg::grid.sync +
//    per-thread __threadfence emit buffer_wbl2/buffer_inv from ALL 512 threads
//    x 256 blocks x 6 syncs => ~70us per sync of L2-maintenance serialization.
//  * This round: same fused stage DAG (proven correct), custom generation
//    barrier with thread0-only fences/atomics (same fence instructions CG
//    uses, 1/512 the count). Plain launch: 78KB LDS -> 1 block/CU -> all 256
//    blocks co-resident.

typedef __attribute__((ext_vector_type(8))) short short8;   // 8 bf16 (4 VGPR)
typedef __attribute__((ext_vector_type(4))) float f32x4;

// ---------- bf16 pack helpers (RNE) ----------
__device__ __forceinline__ uint32_t f2bf(float f) {
  uint32_t x = __float_as_uint(f);
  return (x + 0x7FFFu + ((x >> 16) & 1u)) >> 16;
}
__device__ __forceinline__ uint32_t pack_bf(float re, float im) {
  return f2bf(re) | (f2bf(im) << 16);
}
__device__ __forceinline__ float bf_re(uint32_t u) { return __uint_as_float(u << 16); }
__device__ __forceinline__ float bf_im(uint32_t u) { return __uint_as_float(u & 0xFFFF0000u); }

// fragment-major index for W: B-operand of mfma_f32_16x16x32_bf16
__device__ __forceinline__ int fragIdx(int d, int o, int part, int kk) {
  const int ks = part * 2 + (kk >> 5);
  const int k32 = kk & 31;
  const int nt = o >> 4;
  const int lane = ((k32 >> 3) << 4) | (o & 15);
  return (((d * 16 + ks * 4 + nt) * 64) + lane) * 8 + (k32 & 7);
}

// ===========================================================================
// Lightweight grid barrier (generation + parity counters, thread0-only).
// Device globals are zero-initialized at module load; the barrier leaves
// cnt[]==0 after each use and gen monotonically increasing, so it is safe
// across hipGraph replays. Fences: release=agent (buffer_wbl2) before
// arrive, acquire=agent (buffer_inv) after release — the SAME instructions
// cg::grid.sync uses (proven correct in R10), but 1 thread/block not 512.
// ===========================================================================
__device__ unsigned g_cnt[2];
__device__ unsigned g_gen;

__device__ __forceinline__ void gbar(int nblk) {
  __syncthreads();                       // drains each wave's vmcnt before s_barrier
  if (threadIdx.x == 0) {
    __builtin_amdgcn_fence(__ATOMIC_RELEASE, "agent");   // wbl2: publish our writes
    const unsigned g = __hip_atomic_load(&g_gen, __ATOMIC_RELAXED,
                                         __HIP_MEMORY_SCOPE_AGENT);
    unsigned* c = &g_cnt[g & 1u];
    const unsigned prev = __hip_atomic_fetch_add(c, 1u, __ATOMIC_RELAXED,
                                                 __HIP_MEMORY_SCOPE_AGENT);
    if (prev == (unsigned)nblk - 1u) {
      __hip_atomic_store(c, 0u, __ATOMIC_RELAXED, __HIP_MEMORY_SCOPE_AGENT);
      __hip_atomic_store(&g_gen, g + 1u, __ATOMIC_RELEASE,
                         __HIP_MEMORY_SCOPE_AGENT);
    } else {
      while (__hip_atomic_load(&g_gen, __ATOMIC_RELAXED,
                               __HIP_MEMORY_SCOPE_AGENT) == g)
        __builtin_amdgcn_s_sleep(2);
    }
    __builtin_amdgcn_fence(__ATOMIC_ACQUIRE, "agent");   // inv: see others' writes
  }
  __syncthreads();
}

// ===========================================================================
// Device-function phases (512 threads/block). fp32 compute uses tid<256 —
// identical math to the verified R9 kernels -> bit-identical results.
// ===========================================================================

// dst = A @ A (128x128 complex, fp32). tile 0..63 = 8x8 grid of 16x16.
__device__ __forceinline__ void matsq_dev(
    const float* __restrict__ ar, const float* __restrict__ ai,
    int fromPlanes, const float2* __restrict__ src, float2* __restrict__ dst,
    int tileId, unsigned char* smemraw) {
  float2* band  = (float2*)smemraw;             // 16*128 (16 KB)
  float2* panel = (float2*)(smemraw + 16384);   // 32*128 (32 KB)
  const int tid = threadIdx.x;
  const int ib = tileId >> 3, jb = tileId & 7;
  for (int idx = tid; idx < 16 * HH; idx += 512) {
    const int e = (ib * 16 + (idx >> 7)) * HH + (idx & 127);
    band[idx] = fromPlanes ? make_float2(ar[e], ai[e]) : src[e];
  }
  const int jt = tid & 15, it = (tid >> 4) & 15;
  float sre = 0.f, sim = 0.f;
  for (int kp = 0; kp < 4; ++kp) {
    __syncthreads();
    for (int idx = tid; idx < 32 * HH; idx += 512) {
      const int e = (kp * 32 + (idx >> 7)) * HH + (idx & 127);
      panel[idx] = fromPlanes ? make_float2(ar[e], ai[e]) : src[e];
    }
    __syncthreads();
    if (tid < 256) {
#pragma unroll 4
      for (int kk = 0; kk < 32; ++kk) {
        const float2 a = band[it * HH + kp * 32 + kk];
        const float2 bv = panel[kk * HH + jb * 16 + jt];
        sre = fmaf(a.x, bv.x, sre); sre = fmaf(-a.y, bv.y, sre);
        sim = fmaf(a.x, bv.y, sim); sim = fmaf(a.y, bv.x, sim);
      }
    }
  }
  if (tid < 256)
    dst[(ib * 16 + it) * HH + jb * 16 + jt] = make_float2(sre, sim);
}

// dst(128x64) = A(128x128) @ src(128x64), complex fp32. tile 0..7 = 16 rows.
__device__ __forceinline__ void pmul_dev(
    const float* __restrict__ ar, const float* __restrict__ ai, int aPlanes,
    const float2* __restrict__ Aflat,
    const float* __restrict__ sr, const float* __restrict__ si, int sPlanes,
    const float2* __restrict__ src,
    float2* __restrict__ dst, int tile, unsigned char* smemraw) {
  float2* Pl = (float2*)smemraw;   // 8192 float2 (64 KB)
  const int tid = threadIdx.x;
  if (sPlanes) {
    for (int idx = tid; idx < 8192; idx += 512)
      Pl[idx] = make_float2(sr[idx], si[idx]);
  } else {
    const float4* s4 = (const float4*)src;
    float4* d4 = (float4*)Pl;
    for (int idx = tid; idx < 4096; idx += 512) d4[idx] = s4[idx];
  }
  __syncthreads();
  if (tid < 256) {
    const int i = tile * 16 + (tid >> 4);
    const int c0 = (tid & 15) * 4;
    float accr[4] = {0.f, 0.f, 0.f, 0.f}, acim[4] = {0.f, 0.f, 0.f, 0.f};
#pragma unroll 4
    for (int k = 0; k < 128; ++k) {
      const float2 a = aPlanes ? make_float2(ar[i * 128 + k], ai[i * 128 + k])
                               : Aflat[i * 128 + k];
      const float4 p01 = *(const float4*)&Pl[k * 64 + c0];
      const float4 p23 = *(const float4*)&Pl[k * 64 + c0 + 2];
      accr[0] = fmaf(a.x, p01.x, fmaf(-a.y, p01.y, accr[0]));
      acim[0] = fmaf(a.x, p01.y, fmaf(a.y, p01.x, acim[0]));
      accr[1] = fmaf(a.x, p01.z, fmaf(-a.y, p01.w, accr[1]));
      acim[1] = fmaf(a.x, p01.w, fmaf(a.y, p01.z, acim[1]));
      accr[2] = fmaf(a.x, p23.x, fmaf(-a.y, p23.y, accr[2]));
      acim[2] = fmaf(a.x, p23.y, fmaf(a.y, p23.x, acim[2]));
      accr[3] = fmaf(a.x, p23.z, fmaf(-a.y, p23.w, accr[3]));
      acim[3] = fmaf(a.x, p23.w, fmaf(a.y, p23.z, acim[3]));
    }
#pragma unroll
    for (int cc = 0; cc < 4; ++cc)
      dst[i * 64 + c0 + cc] = make_float2(accr[cc], acim[cc]);
  }
}

// V_d = i^d * Wo * P_d -> fragment-major bf16. tile 0..3 = 16 output rows.
__device__ __forceinline__ void makeV_dev(
    const float2* __restrict__ P,
    const float* __restrict__ wor, const float* __restrict__ woi,
    short* __restrict__ Wf, int d, int tile, unsigned char* smemraw) {
  float2* Pl = (float2*)smemraw;
  const int tid = threadIdx.x;
  const float4* s4 = (const float4*)(P + (size_t)d * 8192);
  float4* d4 = (float4*)Pl;
  for (int idx = tid; idx < 4096; idx += 512) d4[idx] = s4[idx];
  __syncthreads();
  if (tid < 256) {
    const int o = tile * 16 + (tid >> 4);
    const int c0 = (tid & 15) * 4;
    float accr[4] = {0.f, 0.f, 0.f, 0.f}, acim[4] = {0.f, 0.f, 0.f, 0.f};
#pragma unroll 4
    for (int k = 0; k < 128; ++k) {
      const float2 a = make_float2(wor[o * 128 + k], woi[o * 128 + k]);
      const float4 p01 = *(const float4*)&Pl[k * 64 + c0];
      const float4 p23 = *(const float4*)&Pl[k * 64 + c0 + 2];
      accr[0] = fmaf(a.x, p01.x, fmaf(-a.y, p01.y, accr[0]));
      acim[0] = fmaf(a.x, p01.y, fmaf(a.y, p01.x, acim[0]));
      accr[1] = fmaf(a.x, p01.z, fmaf(-a.y, p01.w, accr[1]));
      acim[1] = fmaf(a.x, p01.w, fmaf(a.y, p01.z, acim[1]));
      accr[2] = fmaf(a.x, p23.x, fmaf(-a.y, p23.y, accr[2]));
      acim[2] = fmaf(a.x, p23.y, fmaf(a.y, p23.x, acim[2]));
      accr[3] = fmaf(a.x, p23.z, fmaf(-a.y, p23.w, accr[3]));
      acim[3] = fmaf(a.x, p23.w, fmaf(a.y, p23.z, acim[3]));
    }
#pragma unroll
    for (int cc = 0; cc < 4; ++cc) {
      const float re = accr[cc], im = acim[cc];
      float tr, ti;
      switch (d & 3) {                 // multiply by i^d
        case 0: tr = re;  ti = im;  break;
        case 1: tr = -im; ti = re;  break;
        case 2: tr = -re; ti = -im; break;
        default: tr = im; ti = -re; break;
      }
      const int kk = c0 + cc;
      Wf[fragIdx(d, o, 0, kk)] = (short)f2bf(tr);    // Re(V)  (x_re column)
      Wf[fragIdx(d, o, 1, kk)] = (short)f2bf(-ti);   // -Im(V) (x_im column)
    }
  }
}

// The conv GEMM phase. 256 blocks x 512 thr. Block: b = blk&15, 256-row tile.
// 8 waves: wr = w>>1 owns rows wr*64..+63, nh = w&1 owns out cols nh*32..+31.
__device__ __forceinline__ void conv_dev(
    const float* __restrict__ xr, const float* __restrict__ xi,
    const short* __restrict__ Wf, float* __restrict__ out,
    unsigned char* smemraw) {
  short* xs = (short*)smemraw;   // [288][136] bf16: [re(64)|im(64)|pad8]
  const int tid = threadIdx.x;
  const int blk = blockIdx.x;
  const int b = blk & 15;
  const int t0 = (blk >> 4) * 256;

  // stage x tile (fp32 -> bf16)
  for (int idx = tid; idx < 288 * 16; idx += 512) {
    const int r = idx >> 4;
    const int kq = (idx & 15) << 2;
    const int t = t0 + r - 32;
    uint32_t r01 = 0u, r23 = 0u, i01 = 0u, i23 = 0u;
    if (t >= 0) {
      const size_t g = ((size_t)b * TT + t) * 64 + kq;
      const float4 vr = *(const float4*)(xr + g);
      const float4 vi = *(const float4*)(xi + g);
      r01 = f2bf(vr.x) | (f2bf(vr.y) << 16);
      r23 = f2bf(vr.z) | (f2bf(vr.w) << 16);
      i01 = f2bf(vi.x) | (f2bf(vi.y) << 16);
      i23 = f2bf(vi.z) | (f2bf(vi.w) << 16);
    }
    *(uint2*)&xs[r * 136 + kq]      = make_uint2(r01, r23);
    *(uint2*)&xs[r * 136 + 64 + kq] = make_uint2(i01, i23);
  }
  __syncthreads();

  const int w = tid >> 6;
  const int lane = tid & 63;
  const int wr = w >> 1;        // row group 0..3
  const int nh = w & 1;         // col half 0..1
  const int lm = lane & 15;
  const int kc8 = (lane >> 4) << 3;
  f32x4 acc[4][2];
#pragma unroll
  for (int mi = 0; mi < 4; ++mi)
#pragma unroll
    for (int n = 0; n < 2; ++n) acc[mi][n] = (f32x4){0.f, 0.f, 0.f, 0.f};

#pragma unroll 1
  for (int d = 0; d < TAPS; ++d) {
    const int rb = 32 - d + wr * 64 + lm;
#pragma unroll
    for (int ks = 0; ks < 4; ++ks) {
      const int col = (ks >> 1) * 64 + (ks & 1) * 32 + kc8;
      short8 bq[2];
#pragma unroll
      for (int n = 0; n < 2; ++n)
        bq[n] = *(const short8*)(Wf +
            (((d * 16 + ks * 4 + nh * 2 + n) * 64 + lane) << 3));
      short8 aq[4];
#pragma unroll
      for (int mi = 0; mi < 4; ++mi)
        aq[mi] = *(const short8*)&xs[(rb + mi * 16) * 136 + col];
#pragma unroll
      for (int mi = 0; mi < 4; ++mi)
#pragma unroll
        for (int n = 0; n < 2; ++n)
          acc[mi][n] = __builtin_amdgcn_mfma_f32_16x16x32_bf16(
              aq[mi], bq[n], acc[mi][n], 0, 0, 0);
    }
  }

  // store: D[m][n]: m = (lane>>4)*4 + reg, n = lane&15  (verified C/D layout)
  const int mrow = wr * 64 + ((lane >> 4) << 2);
#pragma unroll
  for (int mi = 0; mi < 4; ++mi) {
#pragma unroll
    for (int n = 0; n < 2; ++n) {
      const int o = (nh * 2 + n) * 16 + lm;
      float* p = out + ((size_t)b * TT + t0 + mrow + mi * 16) * 64 + o;
#pragma unroll
      for (int rg = 0; rg < 4; ++rg) p[(size_t)rg * 64] = acc[mi][n][rg];
    }
  }
}

// ===========================================================================
// The fused kernel: 256 blocks x 512 threads, 6 custom grid barriers.
// Stage plan (dependency depth 6):
//   S0: Wh^2; P_0=Wi copy; P_1=Wh*Wi      S3: Wh^16; P_8..15
//   S1: Wh^4; P_2..3                      S4: P_16..31; V_0..15
//   S2: Wh^8; P_4..7                      S5: V_16..31
//   S6: conv GEMM (all 256 blocks)
// ===========================================================================
__global__ __launch_bounds__(512, 2) void k_all(
    const float* __restrict__ xr, const float* __restrict__ xi,
    const float* __restrict__ wir, const float* __restrict__ wii,
    const float* __restrict__ whr, const float* __restrict__ whi,
    const float* __restrict__ wor, const float* __restrict__ woi,
    float2* __restrict__ ws, float* __restrict__ out) {
  __shared__ __align__(16) unsigned char smem[78336];
  float2* Wp0 = ws;                   // Wh^2
  float2* Wp1 = Wp0 + 16384;          // Wh^4
  float2* Wp2 = Wp1 + 16384;          // Wh^8
  float2* Wp3 = Wp2 + 16384;          // Wh^16
  float2* P   = Wp3 + 16384;          // P_d, d=0..31 (32 x 8192 float2)
  short*  Wfr = (short*)(P + (size_t)32 * 8192);
  const int blk = blockIdx.x;
  const int tid = threadIdx.x;
  const int NB = (int)gridDim.x;

  // ---- S0: Wh^2 ; P_0 ; P_1 ----  (dummy src ptrs = Wp1: valid, unwritten)
  if (blk < 64) {
    matsq_dev(whr, whi, 1, Wp1, Wp0, blk, smem);
  } else if (blk < 80) {
    const int idx = (blk - 64) * 512 + tid;           // exactly 8192
    P[idx] = make_float2(wir[idx], wii[idx]);
  } else if (blk < 88) {
    pmul_dev(whr, whi, 1, Wp1, wir, wii, 1, Wp1, P + 8192, blk - 80, smem);
  }
  gbar(NB);

  // ---- S1: Wh^4 ; P_2..3 ----
  if (blk < 64) {
    matsq_dev(whr, whi, 0, Wp0, Wp1, blk, smem);
  } else if (blk < 80) {
    const int j = (blk - 64) >> 3;
    pmul_dev(whr, whi, 0, Wp0, wir, wii, 0, P + (size_t)j * 8192,
             P + (size_t)(2 + j) * 8192, (blk - 64) & 7, smem);
  }
  gbar(NB);

  // ---- S2: Wh^8 ; P_4..7 ----
  if (blk < 64) {
    matsq_dev(whr, whi, 0, Wp1, Wp2, blk, smem);
  } else if (blk < 96) {
    const int j = (blk - 64) >> 3;
    pmul_dev(whr, whi, 0, Wp1, wir, wii, 0, P + (size_t)j * 8192,
             P + (size_t)(4 + j) * 8192, (blk - 64) & 7, smem);
  }
  gbar(NB);

  // ---- S3: Wh^16 ; P_8..15 ----
  if (blk < 64) {
    matsq_dev(whr, whi, 0, Wp2, Wp3, blk, smem);
  } else if (blk < 128) {
    const int j = (blk - 64) >> 3;
    pmul_dev(whr, whi, 0, Wp2, wir, wii, 0, P + (size_t)j * 8192,
             P + (size_t)(8 + j) * 8192, (blk - 64) & 7, smem);
  }
  gbar(NB);

  // ---- S4: P_16..31 ; V_0..15 ----
  if (blk < 128) {
    const int j = blk >> 3;
    pmul_dev(whr, whi, 0, Wp3, wir, wii, 0, P + (size_t)j * 8192,
             P + (size_t)(16 + j) * 8192, blk & 7, smem);
  } else if (blk < 192) {
    makeV_dev(P, wor, woi, Wfr, (blk - 128) >> 2, (blk - 128) & 3, smem);
  }
  gbar(NB);

  // ---- S5: V_16..31 ----
  if (blk < 64) {
    makeV_dev(P, wor, woi, Wfr, 16 + (blk >> 2), blk & 3, smem);
  }
  gbar(NB);

  // ---- S6: conv GEMM ----
  conv_dev(xr, xi, Wfr, out, smem);
}

// ---------------------------------------------------------------------------
// FALLBACK (R8, proven 596 us): single fused truncated-scan kernel.
// Used only if ws_size < 3 MB.
// ---------------------------------------------------------------------------
__global__ __launch_bounds__(256) void k_fused(
    const float* __restrict__ xr, const float* __restrict__ xi,
    const float* __restrict__ wir, const float* __restrict__ wii,
    const float* __restrict__ whr, const float* __restrict__ whi,
    const float* __restrict__ wor, const float* __restrict__ woi,
    float* __restrict__ out) {
  __shared__ __align__(16) unsigned char smem[63488];
  uint32_t* xpl  = (uint32_t*)smem;
  uint32_t* wiq  = (uint32_t*)(smem + 49152);
  uint32_t* xtq  = (uint32_t*)(smem + 57344);
  float2*   part = (float2*)(smem + 49152);
  float2*   hbuf = (float2*)(smem + 59392);
  uint32_t* woA  = (uint32_t*)smem;
  const int tid = threadIdx.x;
  const int c = blockIdx.x >> 4;
  const int b = blockIdx.x & 15;
  const int t0 = c * LCH - WARM;

  const int ho = tid & 31;
  const int tg = tid >> 5;
  float accr[4][12], acci[4][12];
#pragma unroll
  for (int a = 0; a < 4; ++a)
#pragma unroll
    for (int t = 0; t < 12; ++t) { accr[a][t] = 0.f; acci[a][t] = 0.f; }

#pragma unroll 1
  for (int q = 0; q < 4; ++q) {
    if (q) __syncthreads();
    for (int idx = tid; idx < 16 * HH; idx += 256) {
      const int dd = idx & 15, h = idx >> 4;
      const int g = h * DIN + q * 16 + dd;
      wiq[dd * 128 + h] = pack_bf(wir[g], wii[g]);
    }
    for (int idx = tid; idx < 16 * SS; idx += 256) {
      const int dd = idx & 15, s = idx >> 4;
      const int t = t0 + s;
      uint32_t v = 0u;
      if (t >= 0) {
        const size_t g = ((size_t)b * TT + t) * DIN + q * 16 + dd;
        v = pack_bf(xr[g], xi[g]);
      }
      xtq[dd * 96 + s] = v;
    }
    __syncthreads();
#pragma unroll 4
    for (int dd = 0; dd < 16; ++dd) {
      const uint4 wv  = *(const uint4*)&wiq[dd * 128 + ho * 4];
      const uint4 xv0 = *(const uint4*)&xtq[dd * 96 + tg * 12];
      const uint4 xv1 = *(const uint4*)&xtq[dd * 96 + tg * 12 + 4];
      const uint4 xv2 = *(const uint4*)&xtq[dd * 96 + tg * 12 + 8];
      float wre[4], wim[4], xre[12], xim[12];
      wre[0] = bf_re(wv.x); wim[0] = bf_im(wv.x);
      wre[1] = bf_re(wv.y); wim[1] = bf_im(wv.y);
      wre[2] = bf_re(wv.z); wim[2] = bf_im(wv.z);
      wre[3] = bf_re(wv.w); wim[3] = bf_im(wv.w);
      xre[0] = bf_re(xv0.x); xim[0] = bf_im(xv0.x);
      xre[1] = bf_re(xv0.y); xim[1] = bf_im(xv0.y);
      xre[2] = bf_re(xv0.z); xim[2] = bf_im(xv0.z);
      xre[3] = bf_re(xv0.w); xim[3] = bf_im(xv0.w);
      xre[4] = bf_re(xv1.x); xim[4] = bf_im(xv1.x);
      xre[5] = bf_re(xv1.y); xim[5] = bf_im(xv1.y);
      xre[6] = bf_re(xv1.z); xim[6] = bf_im(xv1.z);
      xre[7] = bf_re(xv1.w); xim[7] = bf_im(xv1.w);
      xre[8] = bf_re(xv2.x); xim[8] = bf_im(xv2.x);
      xre[9] = bf_re(xv2.y); xim[9] = bf_im(xv2.y);
      xre[10] = bf_re(xv2.z); xim[10] = bf_im(xv2.z);
      xre[11] = bf_re(xv2.w); xim[11] = bf_im(xv2.w);
#pragma unroll
      for (int a = 0; a < 4; ++a)
#pragma unroll
        for (int t = 0; t < 12; ++t) {
          accr[a][t] = fmaf(wre[a], xre[t], accr[a][t]);
          accr[a][t] = fmaf(-wim[a], xim[t], accr[a][t]);
          acci[a][t] = fmaf(wre[a], xim[t], acci[a][t]);
          acci[a][t] = fmaf(wim[a], xre[t], acci[a][t]);
        }
    }
  }
  __syncthreads();

#pragma unroll
  for (int tt = 0; tt < 12; ++tt) {
    uint4 v;
    v.x = pack_bf(accr[0][tt], acci[0][tt]);
    v.y = pack_bf(accr[1][tt], acci[1][tt]);
    v.z = pack_bf(accr[2][tt], acci[2][tt]);
    v.w = pack_bf(accr[3][tt], acci[3][tt]);
    *(uint4*)&xpl[(tg * 12 + tt) * 128 + ho * 4] = v;
  }
  if (tid < HH) hbuf[tid] = make_float2(0.f, 0.f);

  const int p8 = tid & 7;
  const int jg = tid >> 3;
  float wr[4][16], wim_[4][16];
#pragma unroll
  for (int a = 0; a < 4; ++a)
#pragma unroll
    for (int i = 0; i < 16; i += 4) {
      const float4 vr = *(const float4*)(whr + (size_t)(jg * 4 + a) * HH + p8 * 16 + i);
      wr[a][i] = vr.x; wr[a][i + 1] = vr.y; wr[a][i + 2] = vr.z; wr[a][i + 3] = vr.w;
      const float4 vi = *(const float4*)(whi + (size_t)(jg * 4 + a) * HH + p8 * 16 + i);
      wim_[a][i] = vi.x; wim_[a][i + 1] = vi.y; wim_[a][i + 2] = vi.z; wim_[a][i + 3] = vi.w;
    }
  __syncthreads();

#pragma unroll 1
  for (int s = 0; s < SS; ++s) {
    const uint32_t u = (tid < HH) ? xpl[s * 128 + tid] : 0u;
    float sre[4] = {0.f, 0.f, 0.f, 0.f}, sim[4] = {0.f, 0.f, 0.f, 0.f};
#pragma unroll
    for (int i = 0; i < 16; ++i) {
      const float2 hv = hbuf[i * 8 + p8];
#pragma unroll
      for (int a = 0; a < 4; ++a) {
        sre[a] = fmaf(wr[a][i], hv.x, sre[a]);
        sre[a] = fmaf(-wim_[a][i], hv.y, sre[a]);
        sim[a] = fmaf(wr[a][i], hv.y, sim[a]);
        sim[a] = fmaf(wim_[a][i], hv.x, sim[a]);
      }
    }
#pragma unroll
    for (int a = 0; a < 4; ++a)
      part[(jg * 4 + a) * 10 + p8] = make_float2(sre[a], sim[a]);
    __syncthreads();
    if (tid < HH) {
      const int j = tid;
      const float4 q0 = *(const float4*)&part[j * 10];
      const float4 q1 = *(const float4*)&part[j * 10 + 2];
      const float4 q2 = *(const float4*)&part[j * 10 + 4];
      const float4 q3 = *(const float4*)&part[j * 10 + 6];
      const float R = ((q0.x + q0.z) + (q1.x + q1.z)) + ((q2.x + q2.z) + (q3.x + q3.z));
      const float I = ((q0.y + q0.w) + (q1.y + q1.w)) + ((q2.y + q2.w) + (q3.y + q3.w));
      const float hr = bf_re(u) - I;
      const float hi = bf_im(u) + R;
      hbuf[(j & 15) * 8 + (j >> 4)] = make_float2(hr, hi);
      if (s >= WARM) xpl[s * 128 + j] = pack_bf(hr, hi);
    }
    __syncthreads();
  }

  const int og = tid & 15;
  const int tg2 = tid >> 4;
  float orr[4][4];
#pragma unroll
  for (int a = 0; a < 4; ++a)
#pragma unroll
    for (int t = 0; t < 4; ++t) orr[a][t] = 0.f;
#pragma unroll 1
  for (int kp = 0; kp < 2; ++kp) {
    __syncthreads();
    for (int idx = tid; idx < DOUT * 64; idx += 256) {
      const int o = idx >> 6, hh = idx & 63;
      woA[hh * 64 + o] = pack_bf(wor[(size_t)o * HH + kp * 64 + hh],
                                 woi[(size_t)o * HH + kp * 64 + hh]);
    }
    __syncthreads();
    for (int hh = 0; hh < 64; ++hh) {
      const uint4 wv = *(const uint4*)&woA[hh * 64 + og * 4];
      float wre[4], wimv[4];
      wre[0] = bf_re(wv.x); wimv[0] = bf_im(wv.x);
      wre[1] = bf_re(wv.y); wimv[1] = bf_im(wv.y);
      wre[2] = bf_re(wv.z); wimv[2] = bf_im(wv.z);
      wre[3] = bf_re(wv.w); wimv[3] = bf_im(wv.w);
#pragma unroll
      for (int tt = 0; tt < 4; ++tt) {
        const uint32_t hu = xpl[(WARM + tg2 * 4 + tt) * 128 + kp * 64 + hh];
        const float hre = bf_re(hu), him = bf_im(hu);
#pragma unroll
        for (int a = 0; a < 4; ++a) {
          orr[a][tt] = fmaf(wre[a], hre, orr[a][tt]);
          orr[a][tt] = fmaf(-wimv[a], him, orr[a][tt]);
        }
      }
    }
  }
#pragma unroll
  for (int tt = 0; tt < 4; ++tt) {
    float* po = out + ((size_t)b * TT + (size_t)c * LCH + tg2 * 4 + tt) * DOUT + og * 4;
    *(float4*)po = make_float4(orr[0][tt], orr[1][tt], orr[2][tt], orr[3][tt]);
  }
}

// ---------------------------------------------------------------------------
extern "C" void kernel_launch(void* const* d_in, const int* in_sizes, int n_in,
                              void* d_out, int out_size, void* d_ws, size_t ws_size,
                              hipStream_t stream) {
  const float* xr  = (const float*)d_in[0];
  const float* xi  = (const float*)d_in[1];
  const float* wir = (const float*)d_in[2];
  const float* wii = (const float*)d_in[3];
  const float* whr = (const float*)d_in[4];
  const float* whi = (const float*)d_in[5];
  const float* wor = (const float*)d_in[6];
  const float* woi = (const float*)d_in[7];
  float* out = (float*)d_out;
  (void)in_sizes; (void)n_in; (void)out_size;

  const size_t NEED = 3145728;   // 3 MB: Wh powers 512K + P 2M + W_frag 512K
  if (ws_size >= NEED) {
    // Plain launch: 78336 B LDS -> max 1 block/CU -> 256 blocks on 256 CUs
    // are all co-resident; the custom gbar() barrier is safe.
    k_all<<<256, 512, 0, stream>>>(xr, xi, wir, wii, whr, whi, wor, woi,
                                   (float2*)d_ws, out);
  } else {
    k_fused<<<(TT / LCH) * BB, 256, 0, stream>>>(
        xr, xi, wir, wii, whr, whi, wor, woi, out);
  }
}

// Round 3
// 195.188 us; speedup vs baseline: 3.1056x; 1.3996x over previous
//
#include <hip/hip_runtime.h>
#include <stdint.h>

// Problem constants
#define BB   16
#define TT   4096
#define DIN  64
#define DOUT 64
#define HH   128
#define LCH  64
#define WARM 32
#define SS   96
#define TAPS 32   // validated: R8's 32-step truncation gave absmax == exact path

// HARD-WON FACTS (rounds 0-11):
//  * d_out = 4,194,304 float32 (16 MB): REAL PART only, flat (b*4096+t)*64+o.
//  * 32-tap history truncation is numerically free (absmax 0.0625 == exact).
//  * R9: 11-kernel chain = 276us (conv 75us + ~200us launch gaps).
//  * R10: cg::grid.sync fusion = 510us (per-thread wbl2/inv fences).
//  * R11: thread0-only gbar = 200us. 6 barriers x (skew + inv + tiny stage
//    on <=1/4 of grid) still dominate; MFMA-busy is only ~13us.
//  * This round: DAG depth 6 -> 1. P_d columns are independent chains
//    p_{d+1} = Wh p_d: 64 worker blocks, Wh slice in VGPRs (loaded once),
//    Wo in padded LDS, V_d written per step. ONE gbar, then conv.

typedef __attribute__((ext_vector_type(8))) short short8;   // 8 bf16 (4 VGPR)
typedef __attribute__((ext_vector_type(4))) float f32x4;

// ---------- bf16 pack helpers (RNE) ----------
__device__ __forceinline__ uint32_t f2bf(float f) {
  uint32_t x = __float_as_uint(f);
  return (x + 0x7FFFu + ((x >> 16) & 1u)) >> 16;
}
__device__ __forceinline__ uint32_t pack_bf(float re, float im) {
  return f2bf(re) | (f2bf(im) << 16);
}
__device__ __forceinline__ float bf_re(uint32_t u) { return __uint_as_float(u << 16); }
__device__ __forceinline__ float bf_im(uint32_t u) { return __uint_as_float(u & 0xFFFF0000u); }

// fragment-major index for W: B-operand of mfma_f32_16x16x32_bf16
// lane = (k32>>3)*16 + (o&15), j = k32&7; frag id = d*16 + ks*4 + nt
__device__ __forceinline__ int fragIdx(int d, int o, int part, int kk) {
  const int ks = part * 2 + (kk >> 5);
  const int k32 = kk & 31;
  const int nt = o >> 4;
  const int lane = ((k32 >> 3) << 4) | (o & 15);
  return (((d * 16 + ks * 4 + nt) * 64) + lane) * 8 + (k32 & 7);
}

// ===========================================================================
// Lightweight grid barrier (generation + parity counters, thread0-only).
// Proven correct+cheap in R11. Device globals zero-init at module load;
// leaves cnt[]==0 after use, gen monotonic -> safe across graph replays.
// ===========================================================================
__device__ unsigned g_cnt[2];
__device__ unsigned g_gen;

__device__ __forceinline__ void gbar(int nblk) {
  __syncthreads();                       // drains vmcnt before s_barrier
  if (threadIdx.x == 0) {
    __builtin_amdgcn_fence(__ATOMIC_RELEASE, "agent");   // wbl2: publish writes
    const unsigned g = __hip_atomic_load(&g_gen, __ATOMIC_RELAXED,
                                         __HIP_MEMORY_SCOPE_AGENT);
    unsigned* c = &g_cnt[g & 1u];
    const unsigned prev = __hip_atomic_fetch_add(c, 1u, __ATOMIC_RELAXED,
                                                 __HIP_MEMORY_SCOPE_AGENT);
    if (prev == (unsigned)nblk - 1u) {
      __hip_atomic_store(c, 0u, __ATOMIC_RELAXED, __HIP_MEMORY_SCOPE_AGENT);
      __hip_atomic_store(&g_gen, g + 1u, __ATOMIC_RELEASE,
                         __HIP_MEMORY_SCOPE_AGENT);
    } else {
      while (__hip_atomic_load(&g_gen, __ATOMIC_RELAXED,
                               __HIP_MEMORY_SCOPE_AGENT) == g)
        __builtin_amdgcn_s_sleep(2);
    }
    __builtin_amdgcn_fence(__ATOMIC_ACQUIRE, "agent");   // inv: see others' writes
  }
  __syncthreads();
}

// ===========================================================================
// Worker phase: block kk (0..63) computes the full tap chain for column kk.
//   p_0 = Wi[:,kk];  p_{d+1} = Wh p_d;  V_d[:,kk] = i^d (Wo p_d)
// Thread roles (512 threads):
//   matvec: row mi = t>>2 (0..127), quarter mq = t&3 -> Wh[mi][mq*32..+31]
//           held in 64 VGPRs, loaded ONCE. 4-lane shfl_xor reduce.
//   V:      out vo = t>>3 (0..63),  seg vg = t&7 -> Wo from padded LDS.
//           8-lane shfl_xor reduce; vg==0 lane writes 2 bf16 frags.
// p ping-pong in LDS with +1-per-16 padding (bank-spread for both read
// patterns). No cross-block communication -> no internal barriers.
// ===========================================================================
__device__ __forceinline__ void chain_dev(
    const float* __restrict__ wir, const float* __restrict__ wii,
    const float* __restrict__ whr, const float* __restrict__ whi,
    const float* __restrict__ wor, const float* __restrict__ woi,
    short* __restrict__ Wf, int kk, unsigned char* smemraw) {
  float2* pbuf = (float2*)smemraw;            // [2][136]  (2176 B)
  float2* wo   = (float2*)(smemraw + 2176);   // [64][135] padded (69120 B)
  const int tid = threadIdx.x;
  const int mi = tid >> 2, mq = tid & 3;      // matvec role
  const int vo = tid >> 3, vg = tid & 7;      // V role

  // Wh slice -> registers (one time; stays live across all 32 steps)
  float whre[32], whim[32];
  {
    const float* pr = whr + mi * 128 + mq * 32;
    const float* pi_ = whi + mi * 128 + mq * 32;
#pragma unroll
    for (int s = 0; s < 32; s += 4) {
      const float4 a = *(const float4*)(pr + s);
      whre[s] = a.x; whre[s + 1] = a.y; whre[s + 2] = a.z; whre[s + 3] = a.w;
      const float4 b = *(const float4*)(pi_ + s);
      whim[s] = b.x; whim[s + 1] = b.y; whim[s + 2] = b.z; whim[s + 3] = b.w;
    }
  }
  // Wo -> padded LDS  (idx = o*135 + h + (h>>4))
  for (int idx = tid; idx < 8192; idx += 512) {
    const int o = idx >> 7, h = idx & 127;
    wo[o * 135 + h + (h >> 4)] = make_float2(wor[o * 128 + h], woi[o * 128 + h]);
  }
  // p_0 = Wi[:, kk]
  if (tid < 128)
    pbuf[tid + (tid >> 4)] = make_float2(wir[tid * 64 + kk], wii[tid * 64 + kk]);
  __syncthreads();

  int cur = 0;
#pragma unroll 1
  for (int d = 0; d < TAPS; ++d) {
    const float2* p = pbuf + cur * 136;
    // ---- V_d[:,kk] = Wo * p ----
    float vr = 0.f, vi = 0.f;
    {
      const float2* wrow = wo + vo * 135 + vg * 17;   // h = vg*16+s -> +s
      const float2* prow = p + vg * 17;
#pragma unroll
      for (int s = 0; s < 16; ++s) {
        const float2 a = wrow[s];
        const float2 pv = prow[s];
        vr = fmaf(a.x, pv.x, fmaf(-a.y, pv.y, vr));
        vi = fmaf(a.x, pv.y, fmaf(a.y, pv.x, vi));
      }
    }
    vr += __shfl_xor(vr, 1); vi += __shfl_xor(vi, 1);
    vr += __shfl_xor(vr, 2); vi += __shfl_xor(vi, 2);
    vr += __shfl_xor(vr, 4); vi += __shfl_xor(vi, 4);
    if (vg == 0) {
      float tr, ti;
      switch (d & 3) {                 // multiply by i^d
        case 0: tr = vr;  ti = vi;  break;
        case 1: tr = -vi; ti = vr;  break;
        case 2: tr = -vr; ti = -vi; break;
        default: tr = vi; ti = -vr; break;
      }
      Wf[fragIdx(d, vo, 0, kk)] = (short)f2bf(tr);    // Re(V)
      Wf[fragIdx(d, vo, 1, kk)] = (short)f2bf(-ti);   // -Im(V)
    }
    // ---- p_{d+1} = Wh * p ----
    if (d < TAPS - 1) {
      float nr = 0.f, ni = 0.f;
      const float2* prow = p + mq * 34;               // h = mq*32+s
#pragma unroll
      for (int s = 0; s < 32; ++s) {
        const float2 pv = prow[s + (s >> 4)];
        nr = fmaf(whre[s], pv.x, fmaf(-whim[s], pv.y, nr));
        ni = fmaf(whre[s], pv.y, fmaf(whim[s], pv.x, ni));
      }
      nr += __shfl_xor(nr, 1); ni += __shfl_xor(ni, 1);
      nr += __shfl_xor(nr, 2); ni += __shfl_xor(ni, 2);
      float2* pn = pbuf + (cur ^ 1) * 136;
      if (mq == 0) pn[mi + (mi >> 4)] = make_float2(nr, ni);
    }
    __syncthreads();
    cur ^= 1;
  }
}

// ===========================================================================
// The conv GEMM phase (proven R11 structure). 256 blocks x 512 thr.
// 8 waves: wr = w>>1 owns rows wr*64..+63, nh = w&1 owns out cols nh*32..+31.
// unroll 2 on taps: lets the compiler overlap next-tap bq L2 loads with MFMA.
// ===========================================================================
__device__ __forceinline__ void conv_dev(
    const float* __restrict__ xr, const float* __restrict__ xi,
    const short* __restrict__ Wf, float* __restrict__ out,
    unsigned char* smemraw) {
  short* xs = (short*)smemraw;   // [288][136] bf16: [re(64)|im(64)|pad8]
  const int tid = threadIdx.x;
  const int blk = blockIdx.x;
  const int b = blk & 15;
  const int t0 = (blk >> 4) * 256;

  // stage x tile (fp32 -> bf16)
  for (int idx = tid; idx < 288 * 16; idx += 512) {
    const int r = idx >> 4;
    const int kq = (idx & 15) << 2;
    const int t = t0 + r - 32;
    uint32_t r01 = 0u, r23 = 0u, i01 = 0u, i23 = 0u;
    if (t >= 0) {
      const size_t g = ((size_t)b * TT + t) * 64 + kq;
      const float4 vr = *(const float4*)(xr + g);
      const float4 vi = *(const float4*)(xi + g);
      r01 = f2bf(vr.x) | (f2bf(vr.y) << 16);
      r23 = f2bf(vr.z) | (f2bf(vr.w) << 16);
      i01 = f2bf(vi.x) | (f2bf(vi.y) << 16);
      i23 = f2bf(vi.z) | (f2bf(vi.w) << 16);
    }
    *(uint2*)&xs[r * 136 + kq]      = make_uint2(r01, r23);
    *(uint2*)&xs[r * 136 + 64 + kq] = make_uint2(i01, i23);
  }
  __syncthreads();

  const int w = tid >> 6;
  const int lane = tid & 63;
  const int wr = w >> 1;        // row group 0..3
  const int nh = w & 1;         // col half 0..1
  const int lm = lane & 15;
  const int kc8 = (lane >> 4) << 3;
  f32x4 acc[4][2];
#pragma unroll
  for (int mi = 0; mi < 4; ++mi)
#pragma unroll
    for (int n = 0; n < 2; ++n) acc[mi][n] = (f32x4){0.f, 0.f, 0.f, 0.f};

#pragma unroll 2
  for (int d = 0; d < TAPS; ++d) {
    const int rb = 32 - d + wr * 64 + lm;
#pragma unroll
    for (int ks = 0; ks < 4; ++ks) {
      const int col = (ks >> 1) * 64 + (ks & 1) * 32 + kc8;
      short8 bq[2];
#pragma unroll
      for (int n = 0; n < 2; ++n)
        bq[n] = *(const short8*)(Wf +
            (((d * 16 + ks * 4 + nh * 2 + n) * 64 + lane) << 3));
      short8 aq[4];
#pragma unroll
      for (int mi = 0; mi < 4; ++mi)
        aq[mi] = *(const short8*)&xs[(rb + mi * 16) * 136 + col];
#pragma unroll
      for (int mi = 0; mi < 4; ++mi)
#pragma unroll
        for (int n = 0; n < 2; ++n)
          acc[mi][n] = __builtin_amdgcn_mfma_f32_16x16x32_bf16(
              aq[mi], bq[n], acc[mi][n], 0, 0, 0);
    }
  }

  // store: D[m][n]: m = (lane>>4)*4 + reg, n = lane&15  (verified C/D layout)
  const int mrow = wr * 64 + ((lane >> 4) << 2);
#pragma unroll
  for (int mi = 0; mi < 4; ++mi) {
#pragma unroll
    for (int n = 0; n < 2; ++n) {
      const int o = (nh * 2 + n) * 16 + lm;
      float* p = out + ((size_t)b * TT + t0 + mrow + mi * 16) * 64 + o;
#pragma unroll
      for (int rg = 0; rg < 4; ++rg) p[(size_t)rg * 64] = acc[mi][n][rg];
    }
  }
}

// ===========================================================================
// The fused kernel: 256 blocks x 512 threads, ONE grid barrier.
//   Phase A: blocks 0..63 run the per-column tap chain -> Wf. Others wait.
//   gbar.
//   Phase B: all 256 blocks run the conv GEMM.
// 78336 B LDS -> 1 block/CU -> all 256 blocks co-resident -> gbar safe.
// ===========================================================================
__global__ __launch_bounds__(512, 2) void k_all(
    const float* __restrict__ xr, const float* __restrict__ xi,
    const float* __restrict__ wir, const float* __restrict__ wii,
    const float* __restrict__ whr, const float* __restrict__ whi,
    const float* __restrict__ wor, const float* __restrict__ woi,
    short* __restrict__ Wfr, float* __restrict__ out) {
  __shared__ __align__(16) unsigned char smem[78336];
  const int blk = blockIdx.x;
  const int NB = (int)gridDim.x;

  if (blk < 64)
    chain_dev(wir, wii, whr, whi, wor, woi, Wfr, blk, smem);

  gbar(NB);

  conv_dev(xr, xi, Wfr, out, smem);
}

// ---------------------------------------------------------------------------
// FALLBACK (R8, proven 596 us): single fused truncated-scan kernel.
// Used only if ws_size < 512 KB.
// ---------------------------------------------------------------------------
__global__ __launch_bounds__(256) void k_fused(
    const float* __restrict__ xr, const float* __restrict__ xi,
    const float* __restrict__ wir, const float* __restrict__ wii,
    const float* __restrict__ whr, const float* __restrict__ whi,
    const float* __restrict__ wor, const float* __restrict__ woi,
    float* __restrict__ out) {
  __shared__ __align__(16) unsigned char smem[63488];
  uint32_t* xpl  = (uint32_t*)smem;
  uint32_t* wiq  = (uint32_t*)(smem + 49152);
  uint32_t* xtq  = (uint32_t*)(smem + 57344);
  float2*   part = (float2*)(smem + 49152);
  float2*   hbuf = (float2*)(smem + 59392);
  uint32_t* woA  = (uint32_t*)smem;
  const int tid = threadIdx.x;
  const int c = blockIdx.x >> 4;
  const int b = blockIdx.x & 15;
  const int t0 = c * LCH - WARM;

  const int ho = tid & 31;
  const int tg = tid >> 5;
  float accr[4][12], acci[4][12];
#pragma unroll
  for (int a = 0; a < 4; ++a)
#pragma unroll
    for (int t = 0; t < 12; ++t) { accr[a][t] = 0.f; acci[a][t] = 0.f; }

#pragma unroll 1
  for (int q = 0; q < 4; ++q) {
    if (q) __syncthreads();
    for (int idx = tid; idx < 16 * HH; idx += 256) {
      const int dd = idx & 15, h = idx >> 4;
      const int g = h * DIN + q * 16 + dd;
      wiq[dd * 128 + h] = pack_bf(wir[g], wii[g]);
    }
    for (int idx = tid; idx < 16 * SS; idx += 256) {
      const int dd = idx & 15, s = idx >> 4;
      const int t = t0 + s;
      uint32_t v = 0u;
      if (t >= 0) {
        const size_t g = ((size_t)b * TT + t) * DIN + q * 16 + dd;
        v = pack_bf(xr[g], xi[g]);
      }
      xtq[dd * 96 + s] = v;
    }
    __syncthreads();
#pragma unroll 4
    for (int dd = 0; dd < 16; ++dd) {
      const uint4 wv  = *(const uint4*)&wiq[dd * 128 + ho * 4];
      const uint4 xv0 = *(const uint4*)&xtq[dd * 96 + tg * 12];
      const uint4 xv1 = *(const uint4*)&xtq[dd * 96 + tg * 12 + 4];
      const uint4 xv2 = *(const uint4*)&xtq[dd * 96 + tg * 12 + 8];
      float wre[4], wim[4], xre[12], xim[12];
      wre[0] = bf_re(wv.x); wim[0] = bf_im(wv.x);
      wre[1] = bf_re(wv.y); wim[1] = bf_im(wv.y);
      wre[2] = bf_re(wv.z); wim[2] = bf_im(wv.z);
      wre[3] = bf_re(wv.w); wim[3] = bf_im(wv.w);
      xre[0] = bf_re(xv0.x); xim[0] = bf_im(xv0.x);
      xre[1] = bf_re(xv0.y); xim[1] = bf_im(xv0.y);
      xre[2] = bf_re(xv0.z); xim[2] = bf_im(xv0.z);
      xre[3] = bf_re(xv0.w); xim[3] = bf_im(xv0.w);
      xre[4] = bf_re(xv1.x); xim[4] = bf_im(xv1.x);
      xre[5] = bf_re(xv1.y); xim[5] = bf_im(xv1.y);
      xre[6] = bf_re(xv1.z); xim[6] = bf_im(xv1.z);
      xre[7] = bf_re(xv1.w); xim[7] = bf_im(xv1.w);
      xre[8] = bf_re(xv2.x); xim[8] = bf_im(xv2.x);
      xre[9] = bf_re(xv2.y); xim[9] = bf_im(xv2.y);
      xre[10] = bf_re(xv2.z); xim[10] = bf_im(xv2.z);
      xre[11] = bf_re(xv2.w); xim[11] = bf_im(xv2.w);
#pragma unroll
      for (int a = 0; a < 4; ++a)
#pragma unroll
        for (int t = 0; t < 12; ++t) {
          accr[a][t] = fmaf(wre[a], xre[t], accr[a][t]);
          accr[a][t] = fmaf(-wim[a], xim[t], accr[a][t]);
          acci[a][t] = fmaf(wre[a], xim[t], acci[a][t]);
          acci[a][t] = fmaf(wim[a], xre[t], acci[a][t]);
        }
    }
  }
  __syncthreads();

#pragma unroll
  for (int tt = 0; tt < 12; ++tt) {
    uint4 v;
    v.x = pack_bf(accr[0][tt], acci[0][tt]);
    v.y = pack_bf(accr[1][tt], acci[1][tt]);
    v.z = pack_bf(accr[2][tt], acci[2][tt]);
    v.w = pack_bf(accr[3][tt], acci[3][tt]);
    *(uint4*)&xpl[(tg * 12 + tt) * 128 + ho * 4] = v;
  }
  if (tid < HH) hbuf[tid] = make_float2(0.f, 0.f);

  const int p8 = tid & 7;
  const int jg = tid >> 3;
  float wr[4][16], wim_[4][16];
#pragma unroll
  for (int a = 0; a < 4; ++a)
#pragma unroll
    for (int i = 0; i < 16; i += 4) {
      const float4 vr = *(const float4*)(whr + (size_t)(jg * 4 + a) * HH + p8 * 16 + i);
      wr[a][i] = vr.x; wr[a][i + 1] = vr.y; wr[a][i + 2] = vr.z; wr[a][i + 3] = vr.w;
      const float4 vi = *(const float4*)(whi + (size_t)(jg * 4 + a) * HH + p8 * 16 + i);
      wim_[a][i] = vi.x; wim_[a][i + 1] = vi.y; wim_[a][i + 2] = vi.z; wim_[a][i + 3] = vi.w;
    }
  __syncthreads();

#pragma unroll 1
  for (int s = 0; s < SS; ++s) {
    const uint32_t u = (tid < HH) ? xpl[s * 128 + tid] : 0u;
    float sre[4] = {0.f, 0.f, 0.f, 0.f}, sim[4] = {0.f, 0.f, 0.f, 0.f};
#pragma unroll
    for (int i = 0; i < 16; ++i) {
      const float2 hv = hbuf[i * 8 + p8];
#pragma unroll
      for (int a = 0; a < 4; ++a) {
        sre[a] = fmaf(wr[a][i], hv.x, sre[a]);
        sre[a] = fmaf(-wim_[a][i], hv.y, sre[a]);
        sim[a] = fmaf(wr[a][i], hv.y, sim[a]);
        sim[a] = fmaf(wim_[a][i], hv.x, sim[a]);
      }
    }
#pragma unroll
    for (int a = 0; a < 4; ++a)
      part[(jg * 4 + a) * 10 + p8] = make_float2(sre[a], sim[a]);
    __syncthreads();
    if (tid < HH) {
      const int j = tid;
      const float4 q0 = *(const float4*)&part[j * 10];
      const float4 q1 = *(const float4*)&part[j * 10 + 2];
      const float4 q2 = *(const float4*)&part[j * 10 + 4];
      const float4 q3 = *(const float4*)&part[j * 10 + 6];
      const float R = ((q0.x + q0.z) + (q1.x + q1.z)) + ((q2.x + q2.z) + (q3.x + q3.z));
      const float I = ((q0.y + q0.w) + (q1.y + q1.w)) + ((q2.y + q2.w) + (q3.y + q3.w));
      const float hr = bf_re(u) - I;
      const float hi = bf_im(u) + R;
      hbuf[(j & 15) * 8 + (j >> 4)] = make_float2(hr, hi);
      if (s >= WARM) xpl[s * 128 + j] = pack_bf(hr, hi);
    }
    __syncthreads();
  }

  const int og = tid & 15;
  const int tg2 = tid >> 4;
  float orr[4][4];
#pragma unroll
  for (int a = 0; a < 4; ++a)
#pragma unroll
    for (int t = 0; t < 4; ++t) orr[a][t] = 0.f;
#pragma unroll 1
  for (int kp = 0; kp < 2; ++kp) {
    __syncthreads();
    for (int idx = tid; idx < DOUT * 64; idx += 256) {
      const int o = idx >> 6, hh = idx & 63;
      woA[hh * 64 + o] = pack_bf(wor[(size_t)o * HH + kp * 64 + hh],
                                 woi[(size_t)o * HH + kp * 64 + hh]);
    }
    __syncthreads();
    for (int hh = 0; hh < 64; ++hh) {
      const uint4 wv = *(const uint4*)&woA[hh * 64 + og * 4];
      float wre[4], wimv[4];
      wre[0] = bf_re(wv.x); wimv[0] = bf_im(wv.x);
      wre[1] = bf_re(wv.y); wimv[1] = bf_im(wv.y);
      wre[2] = bf_re(wv.z); wimv[2] = bf_im(wv.z);
      wre[3] = bf_re(wv.w); wimv[3] = bf_im(wv.w);
#pragma unroll
      for (int tt = 0; tt < 4; ++tt) {
        const uint32_t hu = xpl[(WARM + tg2 * 4 + tt) * 128 + kp * 64 + hh];
        const float hre = bf_re(hu), him = bf_im(hu);
#pragma unroll
        for (int a = 0; a < 4; ++a) {
          orr[a][tt] = fmaf(wre[a], hre, orr[a][tt]);
          orr[a][tt] = fmaf(-wimv[a], him, orr[a][tt]);
        }
      }
    }
  }
#pragma unroll
  for (int tt = 0; tt < 4; ++tt) {
    float* po = out + ((size_t)b * TT + (size_t)c * LCH + tg2 * 4 + tt) * DOUT + og * 4;
    *(float4*)po = make_float4(orr[0][tt], orr[1][tt], orr[2][tt], orr[3][tt]);
  }
}

// ---------------------------------------------------------------------------
extern "C" void kernel_launch(void* const* d_in, const int* in_sizes, int n_in,
                              void* d_out, int out_size, void* d_ws, size_t ws_size,
                              hipStream_t stream) {
  const float* xr  = (const float*)d_in[0];
  const float* xi  = (const float*)d_in[1];
  const float* wir = (const float*)d_in[2];
  const float* wii = (const float*)d_in[3];
  const float* whr = (const float*)d_in[4];
  const float* whi = (const float*)d_in[5];
  const float* wor = (const float*)d_in[6];
  const float* woi = (const float*)d_in[7];
  float* out = (float*)d_out;
  (void)in_sizes; (void)n_in; (void)out_size;

  const size_t NEED = 524288;   // Wf fragment buffer: 256K shorts = 512 KB
  if (ws_size >= NEED) {
    k_all<<<256, 512, 0, stream>>>(xr, xi, wir, wii, whr, whi, wor, woi,
                                   (short*)d_ws, out);
  } else {
    k_fused<<<(TT / LCH) * BB, 256, 0, stream>>>(
        xr, xi, wir, wii, whr, whi, wor, woi, out);
  }
}

// Round 5
// 181.515 us; speedup vs baseline: 3.3396x; 1.0753x over previous
//
#include <hip/hip_runtime.h>
#include <stdint.h>

// Problem constants
#define BB   16
#define TT   4096
#define DIN  64
#define DOUT 64
#define HH   128
#define LCH  64
#define WARM 32
#define SS   96
#define TAPS 32   // validated: R8's 32-step truncation gave absmax == exact path

// HARD-WON FACTS (rounds 0-13):
//  * d_out = 4,194,304 float32 (16 MB): REAL PART only, flat (b*4096+t)*64+o.
//  * 32-tap history truncation is numerically free (absmax 0.0625 == exact).
//  * R9: 11-kernel chain = 276us total (conv standalone 75us, 1 wave/SIMD,
//    nt=4 i.e. 4 loads + 4 ds_reads per 16 MFMA).
//  * R10: cg::grid.sync fusion = 510us (per-thread wbl2/inv fences kill it).
//  * R11: thread0-only gbar = 200us (6 barriers x skew+inv still dominate).
//  * R12: depth-1 DAG (per-column chains) + 1 gbar = 123us k_all. But conv
//    got SLOWER than R9 (nt=2 halved MFMA per load event: 4096 ds_read/CU).
//  * R13: tap-split conv — bench infra failed (container), kernel unmeasured.
//    Audited: no OOB, no divergent barriers, fits 256-VGPR cap. Resubmitting.
//  * This round: 8 waves via TAP-split (not N-split): wave (wr,kh) = rows
//    wr*64..+63, taps kh*16..+16, nt=4. R9's 1:4 load:MFMA ratio at 2
//    waves/SIMD + register double-buffered fetch. Pair-reduce via LDS.

typedef __attribute__((ext_vector_type(8))) short short8;   // 8 bf16 (4 VGPR)
typedef __attribute__((ext_vector_type(4))) float f32x4;

// ---------- bf16 pack helpers (RNE) ----------
__device__ __forceinline__ uint32_t f2bf(float f) {
  uint32_t x = __float_as_uint(f);
  return (x + 0x7FFFu + ((x >> 16) & 1u)) >> 16;
}
__device__ __forceinline__ uint32_t pack_bf(float re, float im) {
  return f2bf(re) | (f2bf(im) << 16);
}
__device__ __forceinline__ float bf_re(uint32_t u) { return __uint_as_float(u << 16); }
__device__ __forceinline__ float bf_im(uint32_t u) { return __uint_as_float(u & 0xFFFF0000u); }

// fragment-major index for W: B-operand of mfma_f32_16x16x32_bf16
// lane = (k32>>3)*16 + (o&15), j = k32&7; frag id = d*16 + ks*4 + nt
__device__ __forceinline__ int fragIdx(int d, int o, int part, int kk) {
  const int ks = part * 2 + (kk >> 5);
  const int k32 = kk & 31;
  const int nt = o >> 4;
  const int lane = ((k32 >> 3) << 4) | (o & 15);
  return (((d * 16 + ks * 4 + nt) * 64) + lane) * 8 + (k32 & 7);
}

// ===========================================================================
// Lightweight grid barrier (generation + parity counters, thread0-only).
// Proven correct+cheap in R11/R12. Zero-init device globals; leaves cnt==0
// after use, gen monotonic -> safe across graph replays.
// ===========================================================================
__device__ unsigned g_cnt[2];
__device__ unsigned g_gen;

__device__ __forceinline__ void gbar(int nblk) {
  __syncthreads();
  if (threadIdx.x == 0) {
    __builtin_amdgcn_fence(__ATOMIC_RELEASE, "agent");
    const unsigned g = __hip_atomic_load(&g_gen, __ATOMIC_RELAXED,
                                         __HIP_MEMORY_SCOPE_AGENT);
    unsigned* c = &g_cnt[g & 1u];
    const unsigned prev = __hip_atomic_fetch_add(c, 1u, __ATOMIC_RELAXED,
                                                 __HIP_MEMORY_SCOPE_AGENT);
    if (prev == (unsigned)nblk - 1u) {
      __hip_atomic_store(c, 0u, __ATOMIC_RELAXED, __HIP_MEMORY_SCOPE_AGENT);
      __hip_atomic_store(&g_gen, g + 1u, __ATOMIC_RELEASE,
                         __HIP_MEMORY_SCOPE_AGENT);
    } else {
      while (__hip_atomic_load(&g_gen, __ATOMIC_RELAXED,
                               __HIP_MEMORY_SCOPE_AGENT) == g)
        __builtin_amdgcn_s_sleep(2);
    }
    __builtin_amdgcn_fence(__ATOMIC_ACQUIRE, "agent");
  }
  __syncthreads();
}

// ===========================================================================
// Worker phase (proven R12): block kk (0..63) computes the tap chain for
// column kk: p_0 = Wi[:,kk]; p_{d+1} = Wh p_d; V_d[:,kk] = i^d (Wo p_d).
// ===========================================================================
__device__ __forceinline__ void chain_dev(
    const float* __restrict__ wir, const float* __restrict__ wii,
    const float* __restrict__ whr, const float* __restrict__ whi,
    const float* __restrict__ wor, const float* __restrict__ woi,
    short* __restrict__ Wf, int kk, unsigned char* smemraw) {
  float2* pbuf = (float2*)smemraw;            // [2][136]  (2176 B)
  float2* wo   = (float2*)(smemraw + 2176);   // [64][135] padded (69120 B)
  const int tid = threadIdx.x;
  const int mi = tid >> 2, mq = tid & 3;      // matvec role
  const int vo = tid >> 3, vg = tid & 7;      // V role

  float whre[32], whim[32];
  {
    const float* pr = whr + mi * 128 + mq * 32;
    const float* pi_ = whi + mi * 128 + mq * 32;
#pragma unroll
    for (int s = 0; s < 32; s += 4) {
      const float4 a = *(const float4*)(pr + s);
      whre[s] = a.x; whre[s + 1] = a.y; whre[s + 2] = a.z; whre[s + 3] = a.w;
      const float4 b = *(const float4*)(pi_ + s);
      whim[s] = b.x; whim[s + 1] = b.y; whim[s + 2] = b.z; whim[s + 3] = b.w;
    }
  }
  for (int idx = tid; idx < 8192; idx += 512) {
    const int o = idx >> 7, h = idx & 127;
    wo[o * 135 + h + (h >> 4)] = make_float2(wor[o * 128 + h], woi[o * 128 + h]);
  }
  if (tid < 128)
    pbuf[tid + (tid >> 4)] = make_float2(wir[tid * 64 + kk], wii[tid * 64 + kk]);
  __syncthreads();

  int cur = 0;
#pragma unroll 1
  for (int d = 0; d < TAPS; ++d) {
    const float2* p = pbuf + cur * 136;
    float vr = 0.f, vi = 0.f;
    {
      const float2* wrow = wo + vo * 135 + vg * 17;
      const float2* prow = p + vg * 17;
#pragma unroll
      for (int s = 0; s < 16; ++s) {
        const float2 a = wrow[s];
        const float2 pv = prow[s];
        vr = fmaf(a.x, pv.x, fmaf(-a.y, pv.y, vr));
        vi = fmaf(a.x, pv.y, fmaf(a.y, pv.x, vi));
      }
    }
    vr += __shfl_xor(vr, 1); vi += __shfl_xor(vi, 1);
    vr += __shfl_xor(vr, 2); vi += __shfl_xor(vi, 2);
    vr += __shfl_xor(vr, 4); vi += __shfl_xor(vi, 4);
    if (vg == 0) {
      float tr, ti;
      switch (d & 3) {
        case 0: tr = vr;  ti = vi;  break;
        case 1: tr = -vi; ti = vr;  break;
        case 2: tr = -vr; ti = -vi; break;
        default: tr = vi; ti = -vr; break;
      }
      Wf[fragIdx(d, vo, 0, kk)] = (short)f2bf(tr);
      Wf[fragIdx(d, vo, 1, kk)] = (short)f2bf(-ti);
    }
    if (d < TAPS - 1) {
      float nr = 0.f, ni = 0.f;
      const float2* prow = p + mq * 34;
#pragma unroll
      for (int s = 0; s < 32; ++s) {
        const float2 pv = prow[s + (s >> 4)];
        nr = fmaf(whre[s], pv.x, fmaf(-whim[s], pv.y, nr));
        ni = fmaf(whre[s], pv.y, fmaf(whim[s], pv.x, ni));
      }
      nr += __shfl_xor(nr, 1); ni += __shfl_xor(ni, 1);
      nr += __shfl_xor(nr, 2); ni += __shfl_xor(ni, 2);
      float2* pn = pbuf + (cur ^ 1) * 136;
      if (mq == 0) pn[mi + (mi >> 4)] = make_float2(nr, ni);
    }
    __syncthreads();
    cur ^= 1;
  }
}

// ===========================================================================
// Conv GEMM phase. 256 blocks x 512 thr (8 waves, 2/SIMD).
// Wave w: wr = w>>1 owns rows wr*64..+63; kh = w&1 owns taps kh*16..+16;
// nt = 4 (full N) -> 4 bq + 4 aq per 16 MFMA (R9's proven ratio).
// Register double-buffer: fetch group it+1 while MFMA group it.
// Tap-halves pair-reduced through LDS (padded stride 65), kh==0 stores.
// ===========================================================================
__device__ __forceinline__ void conv_dev(
    const float* __restrict__ xr, const float* __restrict__ xi,
    const short* __restrict__ Wf, float* __restrict__ out,
    unsigned char* smemraw) {
  short* xs = (short*)smemraw;   // [288][136] bf16: [re(64)|im(64)|pad8]
  const int tid = threadIdx.x;
  const int blk = blockIdx.x;
  const int b = blk & 15;
  const int t0 = (blk >> 4) * 256;

  // stage x tile (fp32 -> bf16)
  for (int idx = tid; idx < 288 * 16; idx += 512) {
    const int r = idx >> 4;
    const int kq = (idx & 15) << 2;
    const int t = t0 + r - 32;
    uint32_t r01 = 0u, r23 = 0u, i01 = 0u, i23 = 0u;
    if (t >= 0) {
      const size_t g = ((size_t)b * TT + t) * 64 + kq;
      const float4 vr = *(const float4*)(xr + g);
      const float4 vi = *(const float4*)(xi + g);
      r01 = f2bf(vr.x) | (f2bf(vr.y) << 16);
      r23 = f2bf(vr.z) | (f2bf(vr.w) << 16);
      i01 = f2bf(vi.x) | (f2bf(vi.y) << 16);
      i23 = f2bf(vi.z) | (f2bf(vi.w) << 16);
    }
    *(uint2*)&xs[r * 136 + kq]      = make_uint2(r01, r23);
    *(uint2*)&xs[r * 136 + 64 + kq] = make_uint2(i01, i23);
  }
  __syncthreads();

  const int w = tid >> 6;
  const int lane = tid & 63;
  const int wr = w >> 1;        // row group 0..3
  const int kh = w & 1;         // tap half 0..1
  const int lm = lane & 15;
  const int kc8 = (lane >> 4) << 3;

  f32x4 acc[4][4];
#pragma unroll
  for (int mi = 0; mi < 4; ++mi)
#pragma unroll
    for (int nt = 0; nt < 4; ++nt) acc[mi][nt] = (f32x4){0.f, 0.f, 0.f, 0.f};

  // fetch helper: it in [0,64): d = kh*16 + (it>>2), ks = it&3
  short8 aqA[4], bqA[4], aqB[4], bqB[4];
#define FETCH(IT, AQ, BQ)                                                     \
  do {                                                                        \
    const int d_ = kh * 16 + ((IT) >> 2);                                     \
    const int ks_ = (IT) & 3;                                                 \
    const int rb_ = 32 - d_ + wr * 64 + lm;                                   \
    const int col_ = (ks_ >> 1) * 64 + (ks_ & 1) * 32 + kc8;                  \
    _Pragma("unroll")                                                         \
    for (int nt_ = 0; nt_ < 4; ++nt_)                                         \
      BQ[nt_] = *(const short8*)(Wf +                                         \
          (((d_ * 16 + ks_ * 4 + nt_) * 64 + lane) << 3));                    \
    _Pragma("unroll")                                                         \
    for (int mi_ = 0; mi_ < 4; ++mi_)                                         \
      AQ[mi_] = *(const short8*)&xs[(rb_ + mi_ * 16) * 136 + col_];           \
  } while (0)

#define MFMAGRP(AQ, BQ)                                                       \
  do {                                                                        \
    _Pragma("unroll")                                                         \
    for (int mi_ = 0; mi_ < 4; ++mi_)                                         \
      _Pragma("unroll")                                                       \
      for (int nt_ = 0; nt_ < 4; ++nt_)                                       \
        acc[mi_][nt_] = __builtin_amdgcn_mfma_f32_16x16x32_bf16(              \
            AQ[mi_], BQ[nt_], acc[mi_][nt_], 0, 0, 0);                        \
  } while (0)

  FETCH(0, aqA, bqA);
#pragma unroll 1
  for (int it = 0; it < 62; it += 2) {
    FETCH(it + 1, aqB, bqB);
    MFMAGRP(aqA, bqA);
    FETCH(it + 2, aqA, bqA);
    MFMAGRP(aqB, bqB);
  }
  FETCH(63, aqB, bqB);
  MFMAGRP(aqA, bqA);
  MFMAGRP(aqB, bqB);
#undef FETCH
#undef MFMAGRP

  // ---- pair reduction (kh=1 partials -> LDS -> kh=0 adds & stores) ----
  __syncthreads();                 // all waves done reading xs
  float* fred = (float*)smemraw;   // [4][64][65] floats = 66560 B
  if (kh == 1) {
#pragma unroll
    for (int mi = 0; mi < 4; ++mi)
#pragma unroll
      for (int nt = 0; nt < 4; ++nt)
#pragma unroll
        for (int rg = 0; rg < 4; ++rg) {
          const int mloc = ((lane >> 4) << 2) + rg + mi * 16;
          fred[wr * 4160 + mloc * 65 + nt * 16 + lm] = acc[mi][nt][rg];
        }
  }
  __syncthreads();
  if (kh == 0) {
    const int mrow = wr * 64 + ((lane >> 4) << 2);
#pragma unroll
    for (int mi = 0; mi < 4; ++mi) {
#pragma unroll
      for (int nt = 0; nt < 4; ++nt) {
        const int o = nt * 16 + lm;
        float* p = out + ((size_t)b * TT + t0 + mrow + mi * 16) * 64 + o;
#pragma unroll
        for (int rg = 0; rg < 4; ++rg) {
          const int mloc = ((lane >> 4) << 2) + rg + mi * 16;
          p[(size_t)rg * 64] =
              acc[mi][nt][rg] + fred[wr * 4160 + mloc * 65 + o];
        }
      }
    }
  }
}

// ===========================================================================
// The fused kernel: 256 blocks x 512 threads, ONE grid barrier.
//   Phase A: blocks 0..63 run the per-column tap chain -> Wf. Others wait.
//   gbar.  Phase B: all 256 blocks run the conv GEMM.
// 78336 B LDS -> 1 block/CU -> all 256 blocks co-resident -> gbar safe.
// ===========================================================================
__global__ __launch_bounds__(512, 2) void k_all(
    const float* __restrict__ xr, const float* __restrict__ xi,
    const float* __restrict__ wir, const float* __restrict__ wii,
    const float* __restrict__ whr, const float* __restrict__ whi,
    const float* __restrict__ wor, const float* __restrict__ woi,
    short* __restrict__ Wfr, float* __restrict__ out) {
  __shared__ __align__(16) unsigned char smem[78336];
  const int blk = blockIdx.x;
  const int NB = (int)gridDim.x;

  if (blk < 64)
    chain_dev(wir, wii, whr, whi, wor, woi, Wfr, blk, smem);

  gbar(NB);

  conv_dev(xr, xi, Wfr, out, smem);
}

// ---------------------------------------------------------------------------
// FALLBACK (R8, proven 596 us): single fused truncated-scan kernel.
// Used only if ws_size < 512 KB.
// ---------------------------------------------------------------------------
__global__ __launch_bounds__(256) void k_fused(
    const float* __restrict__ xr, const float* __restrict__ xi,
    const float* __restrict__ wir, const float* __restrict__ wii,
    const float* __restrict__ whr, const float* __restrict__ whi,
    const float* __restrict__ wor, const float* __restrict__ woi,
    float* __restrict__ out) {
  __shared__ __align__(16) unsigned char smem[63488];
  uint32_t* xpl  = (uint32_t*)smem;
  uint32_t* wiq  = (uint32_t*)(smem + 49152);
  uint32_t* xtq  = (uint32_t*)(smem + 57344);
  float2*   part = (float2*)(smem + 49152);
  float2*   hbuf = (float2*)(smem + 59392);
  uint32_t* woA  = (uint32_t*)smem;
  const int tid = threadIdx.x;
  const int c = blockIdx.x >> 4;
  const int b = blockIdx.x & 15;
  const int t0 = c * LCH - WARM;

  const int ho = tid & 31;
  const int tg = tid >> 5;
  float accr[4][12], acci[4][12];
#pragma unroll
  for (int a = 0; a < 4; ++a)
#pragma unroll
    for (int t = 0; t < 12; ++t) { accr[a][t] = 0.f; acci[a][t] = 0.f; }

#pragma unroll 1
  for (int q = 0; q < 4; ++q) {
    if (q) __syncthreads();
    for (int idx = tid; idx < 16 * HH; idx += 256) {
      const int dd = idx & 15, h = idx >> 4;
      const int g = h * DIN + q * 16 + dd;
      wiq[dd * 128 + h] = pack_bf(wir[g], wii[g]);
    }
    for (int idx = tid; idx < 16 * SS; idx += 256) {
      const int dd = idx & 15, s = idx >> 4;
      const int t = t0 + s;
      uint32_t v = 0u;
      if (t >= 0) {
        const size_t g = ((size_t)b * TT + t) * DIN + q * 16 + dd;
        v = pack_bf(xr[g], xi[g]);
      }
      xtq[dd * 96 + s] = v;
    }
    __syncthreads();
#pragma unroll 4
    for (int dd = 0; dd < 16; ++dd) {
      const uint4 wv  = *(const uint4*)&wiq[dd * 128 + ho * 4];
      const uint4 xv0 = *(const uint4*)&xtq[dd * 96 + tg * 12];
      const uint4 xv1 = *(const uint4*)&xtq[dd * 96 + tg * 12 + 4];
      const uint4 xv2 = *(const uint4*)&xtq[dd * 96 + tg * 12 + 8];
      float wre[4], wim[4], xre[12], xim[12];
      wre[0] = bf_re(wv.x); wim[0] = bf_im(wv.x);
      wre[1] = bf_re(wv.y); wim[1] = bf_im(wv.y);
      wre[2] = bf_re(wv.z); wim[2] = bf_im(wv.z);
      wre[3] = bf_re(wv.w); wim[3] = bf_im(wv.w);
      xre[0] = bf_re(xv0.x); xim[0] = bf_im(xv0.x);
      xre[1] = bf_re(xv0.y); xim[1] = bf_im(xv0.y);
      xre[2] = bf_re(xv0.z); xim[2] = bf_im(xv0.z);
      xre[3] = bf_re(xv0.w); xim[3] = bf_im(xv0.w);
      xre[4] = bf_re(xv1.x); xim[4] = bf_im(xv1.x);
      xre[5] = bf_re(xv1.y); xim[5] = bf_im(xv1.y);
      xre[6] = bf_re(xv1.z); xim[6] = bf_im(xv1.z);
      xre[7] = bf_re(xv1.w); xim[7] = bf_im(xv1.w);
      xre[8] = bf_re(xv2.x); xim[8] = bf_im(xv2.x);
      xre[9] = bf_re(xv2.y); xim[9] = bf_im(xv2.y);
      xre[10] = bf_re(xv2.z); xim[10] = bf_im(xv2.z);
      xre[11] = bf_re(xv2.w); xim[11] = bf_im(xv2.w);
#pragma unroll
      for (int a = 0; a < 4; ++a)
#pragma unroll
        for (int t = 0; t < 12; ++t) {
          accr[a][t] = fmaf(wre[a], xre[t], accr[a][t]);
          accr[a][t] = fmaf(-wim[a], xim[t], accr[a][t]);
          acci[a][t] = fmaf(wre[a], xim[t], acci[a][t]);
          acci[a][t] = fmaf(wim[a], xre[t], acci[a][t]);
        }
    }
  }
  __syncthreads();

#pragma unroll
  for (int tt = 0; tt < 12; ++tt) {
    uint4 v;
    v.x = pack_bf(accr[0][tt], acci[0][tt]);
    v.y = pack_bf(accr[1][tt], acci[1][tt]);
    v.z = pack_bf(accr[2][tt], acci[2][tt]);
    v.w = pack_bf(accr[3][tt], acci[3][tt]);
    *(uint4*)&xpl[(tg * 12 + tt) * 128 + ho * 4] = v;
  }
  if (tid < HH) hbuf[tid] = make_float2(0.f, 0.f);

  const int p8 = tid & 7;
  const int jg = tid >> 3;
  float wr[4][16], wim_[4][16];
#pragma unroll
  for (int a = 0; a < 4; ++a)
#pragma unroll
    for (int i = 0; i < 16; i += 4) {
      const float4 vr = *(const float4*)(whr + (size_t)(jg * 4 + a) * HH + p8 * 16 + i);
      wr[a][i] = vr.x; wr[a][i + 1] = vr.y; wr[a][i + 2] = vr.z; wr[a][i + 3] = vr.w;
      const float4 vi = *(const float4*)(whi + (size_t)(jg * 4 + a) * HH + p8 * 16 + i);
      wim_[a][i] = vi.x; wim_[a][i + 1] = vi.y; wim_[a][i + 2] = vi.z; wim_[a][i + 3] = vi.w;
    }
  __syncthreads();

#pragma unroll 1
  for (int s = 0; s < SS; ++s) {
    const uint32_t u = (tid < HH) ? xpl[s * 128 + tid] : 0u;
    float sre[4] = {0.f, 0.f, 0.f, 0.f}, sim[4] = {0.f, 0.f, 0.f, 0.f};
#pragma unroll
    for (int i = 0; i < 16; ++i) {
      const float2 hv = hbuf[i * 8 + p8];
#pragma unroll
      for (int a = 0; a < 4; ++a) {
        sre[a] = fmaf(wr[a][i], hv.x, sre[a]);
        sre[a] = fmaf(-wim_[a][i], hv.y, sre[a]);
        sim[a] = fmaf(wr[a][i], hv.y, sim[a]);
        sim[a] = fmaf(wim_[a][i], hv.x, sim[a]);
      }
    }
#pragma unroll
    for (int a = 0; a < 4; ++a)
      part[(jg * 4 + a) * 10 + p8] = make_float2(sre[a], sim[a]);
    __syncthreads();
    if (tid < HH) {
      const int j = tid;
      const float4 q0 = *(const float4*)&part[j * 10];
      const float4 q1 = *(const float4*)&part[j * 10 + 2];
      const float4 q2 = *(const float4*)&part[j * 10 + 4];
      const float4 q3 = *(const float4*)&part[j * 10 + 6];
      const float R = ((q0.x + q0.z) + (q1.x + q1.z)) + ((q2.x + q2.z) + (q3.x + q3.z));
      const float I = ((q0.y + q0.w) + (q1.y + q1.w)) + ((q2.y + q2.w) + (q3.y + q3.w));
      const float hr = bf_re(u) - I;
      const float hi = bf_im(u) + R;
      hbuf[(j & 15) * 8 + (j >> 4)] = make_float2(hr, hi);
      if (s >= WARM) xpl[s * 128 + j] = pack_bf(hr, hi);
    }
    __syncthreads();
  }

  const int og = tid & 15;
  const int tg2 = tid >> 4;
  float orr[4][4];
#pragma unroll
  for (int a = 0; a < 4; ++a)
#pragma unroll
    for (int t = 0; t < 4; ++t) orr[a][t] = 0.f;
#pragma unroll 1
  for (int kp = 0; kp < 2; ++kp) {
    __syncthreads();
    for (int idx = tid; idx < DOUT * 64; idx += 256) {
      const int o = idx >> 6, hh = idx & 63;
      woA[hh * 64 + o] = pack_bf(wor[(size_t)o * HH + kp * 64 + hh],
                                 woi[(size_t)o * HH + kp * 64 + hh]);
    }
    __syncthreads();
    for (int hh = 0; hh < 64; ++hh) {
      const uint4 wv = *(const uint4*)&woA[hh * 64 + og * 4];
      float wre[4], wimv[4];
      wre[0] = bf_re(wv.x); wimv[0] = bf_im(wv.x);
      wre[1] = bf_re(wv.y); wimv[1] = bf_im(wv.y);
      wre[2] = bf_re(wv.z); wimv[2] = bf_im(wv.z);
      wre[3] = bf_re(wv.w); wimv[3] = bf_im(wv.w);
#pragma unroll
      for (int tt = 0; tt < 4; ++tt) {
        const uint32_t hu = xpl[(WARM + tg2 * 4 + tt) * 128 + kp * 64 + hh];
        const float hre = bf_re(hu), him = bf_im(hu);
#pragma unroll
        for (int a = 0; a < 4; ++a) {
          orr[a][tt] = fmaf(wre[a], hre, orr[a][tt]);
          orr[a][tt] = fmaf(-wimv[a], him, orr[a][tt]);
        }
      }
    }
  }
#pragma unroll
  for (int tt = 0; tt < 4; ++tt) {
    float* po = out + ((size_t)b * TT + (size_t)c * LCH + tg2 * 4 + tt) * DOUT + og * 4;
    *(float4*)po = make_float4(orr[0][tt], orr[1][tt], orr[2][tt], orr[3][tt]);
  }
}

// ---------------------------------------------------------------------------
extern "C" void kernel_launch(void* const* d_in, const int* in_sizes, int n_in,
                              void* d_out, int out_size, void* d_ws, size_t ws_size,
                              hipStream_t stream) {
  const float* xr  = (const float*)d_in[0];
  const float* xi  = (const float*)d_in[1];
  const float* wir = (const float*)d_in[2];
  const float* wii = (const float*)d_in[3];
  const float* whr = (const float*)d_in[4];
  const float* whi = (const float*)d_in[5];
  const float* wor = (const float*)d_in[6];
  const float* woi = (const float*)d_in[7];
  float* out = (float*)d_out;
  (void)in_sizes; (void)n_in; (void)out_size;

  const size_t NEED = 524288;   // Wf fragment buffer: 256K shorts = 512 KB
  if (ws_size >= NEED) {
    k_all<<<256, 512, 0, stream>>>(xr, xi, wir, wii, whr, whi, wor, woi,
                                   (short*)d_ws, out);
  } else {
    k_fused<<<(TT / LCH) * BB, 256, 0, stream>>>(
        xr, xi, wir, wii, whr, whi, wor, woi, out);
  }
}

// Round 6
// 177.044 us; speedup vs baseline: 3.4239x; 1.0253x over previous
//
#include <hip/hip_runtime.h>
#include <stdint.h>

// Problem constants
#define BB   16
#define TT   4096
#define DIN  64
#define DOUT 64
#define HH   128
#define LCH  64
#define WARM 32
#define SS   96
#define TAPS 32   // validated: R8's 32-step truncation gave absmax == exact path

// HARD-WON FACTS (rounds 0-14):
//  * d_out = 4,194,304 float32 (16 MB): REAL PART only, flat (b*4096+t)*64+o.
//  * 32-tap history truncation is numerically free (absmax 0.0625 == exact).
//  * R9: 11-kernel chain = 276us (conv standalone 75us). R10: cg sync = 510us.
//  * R11: thread0-only gbar = 200us. R12: depth-1 DAG + 1 gbar = 123us.
//  * R14: tap-split + reg dbuf = 112us. KEY: R12 conv == R14 conv (~90us)
//    despite 2x different load:MFMA ratio -> conv is NOT per-iter latency
//    bound. Invariant = B-operand L2 traffic (2MB/CU, all CUs reading the
//    SAME 512KB Wf in lockstep -> L2 line contention, ~20GB/s/CU effective).
//  * This round: B-tile staged in LDS once per block (4x traffic cut),
//    reg-staged (T14: load early, ds_write late), dbuf across taps; waves =
//    4 row-groups x 2 ks-halves (mi=4,nt=4 ratio); tap-order skew per block
//    decorrelates L2 line requests; x pre-staged before gbar on conv blocks.

typedef __attribute__((ext_vector_type(8))) short short8;   // 8 bf16 (4 VGPR)
typedef __attribute__((ext_vector_type(4))) float f32x4;

// ---------- bf16 pack helpers (RNE) ----------
__device__ __forceinline__ uint32_t f2bf(float f) {
  uint32_t x = __float_as_uint(f);
  return (x + 0x7FFFu + ((x >> 16) & 1u)) >> 16;
}
__device__ __forceinline__ uint32_t pack_bf(float re, float im) {
  return f2bf(re) | (f2bf(im) << 16);
}
__device__ __forceinline__ float bf_re(uint32_t u) { return __uint_as_float(u << 16); }
__device__ __forceinline__ float bf_im(uint32_t u) { return __uint_as_float(u & 0xFFFF0000u); }

// fragment-major index for W: B-operand of mfma_f32_16x16x32_bf16
// lane = (k32>>3)*16 + (o&15), j = k32&7; frag id = d*16 + ks*4 + nt
// => tap d occupies shorts [d*8192, d*8192+8192): frag-contiguous per tap.
__device__ __forceinline__ int fragIdx(int d, int o, int part, int kk) {
  const int ks = part * 2 + (kk >> 5);
  const int k32 = kk & 31;
  const int nt = o >> 4;
  const int lane = ((k32 >> 3) << 4) | (o & 15);
  return (((d * 16 + ks * 4 + nt) * 64) + lane) * 8 + (k32 & 7);
}

// ===========================================================================
// Lightweight grid barrier (generation + parity counters, thread0-only).
// Proven correct+cheap in R11/R12/R14. Zero-init device globals; leaves
// cnt==0 after use, gen monotonic -> safe across graph replays.
// ===========================================================================
__device__ unsigned g_cnt[2];
__device__ unsigned g_gen;

__device__ __forceinline__ void gbar(int nblk) {
  __syncthreads();
  if (threadIdx.x == 0) {
    __builtin_amdgcn_fence(__ATOMIC_RELEASE, "agent");
    const unsigned g = __hip_atomic_load(&g_gen, __ATOMIC_RELAXED,
                                         __HIP_MEMORY_SCOPE_AGENT);
    unsigned* c = &g_cnt[g & 1u];
    const unsigned prev = __hip_atomic_fetch_add(c, 1u, __ATOMIC_RELAXED,
                                                 __HIP_MEMORY_SCOPE_AGENT);
    if (prev == (unsigned)nblk - 1u) {
      __hip_atomic_store(c, 0u, __ATOMIC_RELAXED, __HIP_MEMORY_SCOPE_AGENT);
      __hip_atomic_store(&g_gen, g + 1u, __ATOMIC_RELEASE,
                         __HIP_MEMORY_SCOPE_AGENT);
    } else {
      while (__hip_atomic_load(&g_gen, __ATOMIC_RELAXED,
                               __HIP_MEMORY_SCOPE_AGENT) == g)
        __builtin_amdgcn_s_sleep(2);
    }
    __builtin_amdgcn_fence(__ATOMIC_ACQUIRE, "agent");
  }
  __syncthreads();
}

// ===========================================================================
// Worker phase (proven R12): block kk (0..63) computes the tap chain for
// column kk: p_0 = Wi[:,kk]; p_{d+1} = Wh p_d; V_d[:,kk] = i^d (Wo p_d).
// Uses smem[0 .. 71296).
// ===========================================================================
__device__ __forceinline__ void chain_dev(
    const float* __restrict__ wir, const float* __restrict__ wii,
    const float* __restrict__ whr, const float* __restrict__ whi,
    const float* __restrict__ wor, const float* __restrict__ woi,
    short* __restrict__ Wf, int kk, unsigned char* smemraw) {
  float2* pbuf = (float2*)smemraw;            // [2][136]  (2176 B)
  float2* wo   = (float2*)(smemraw + 2176);   // [64][135] padded (69120 B)
  const int tid = threadIdx.x;
  const int mi = tid >> 2, mq = tid & 3;      // matvec role
  const int vo = tid >> 3, vg = tid & 7;      // V role

  float whre[32], whim[32];
  {
    const float* pr = whr + mi * 128 + mq * 32;
    const float* pi_ = whi + mi * 128 + mq * 32;
#pragma unroll
    for (int s = 0; s < 32; s += 4) {
      const float4 a = *(const float4*)(pr + s);
      whre[s] = a.x; whre[s + 1] = a.y; whre[s + 2] = a.z; whre[s + 3] = a.w;
      const float4 b = *(const float4*)(pi_ + s);
      whim[s] = b.x; whim[s + 1] = b.y; whim[s + 2] = b.z; whim[s + 3] = b.w;
    }
  }
  for (int idx = tid; idx < 8192; idx += 512) {
    const int o = idx >> 7, h = idx & 127;
    wo[o * 135 + h + (h >> 4)] = make_float2(wor[o * 128 + h], woi[o * 128 + h]);
  }
  if (tid < 128)
    pbuf[tid + (tid >> 4)] = make_float2(wir[tid * 64 + kk], wii[tid * 64 + kk]);
  __syncthreads();

  int cur = 0;
#pragma unroll 1
  for (int d = 0; d < TAPS; ++d) {
    const float2* p = pbuf + cur * 136;
    float vr = 0.f, vi = 0.f;
    {
      const float2* wrow = wo + vo * 135 + vg * 17;
      const float2* prow = p + vg * 17;
#pragma unroll
      for (int s = 0; s < 16; ++s) {
        const float2 a = wrow[s];
        const float2 pv = prow[s];
        vr = fmaf(a.x, pv.x, fmaf(-a.y, pv.y, vr));
        vi = fmaf(a.x, pv.y, fmaf(a.y, pv.x, vi));
      }
    }
    vr += __shfl_xor(vr, 1); vi += __shfl_xor(vi, 1);
    vr += __shfl_xor(vr, 2); vi += __shfl_xor(vi, 2);
    vr += __shfl_xor(vr, 4); vi += __shfl_xor(vi, 4);
    if (vg == 0) {
      float tr, ti;
      switch (d & 3) {
        case 0: tr = vr;  ti = vi;  break;
        case 1: tr = -vi; ti = vr;  break;
        case 2: tr = -vr; ti = -vi; break;
        default: tr = vi; ti = -vr; break;
      }
      Wf[fragIdx(d, vo, 0, kk)] = (short)f2bf(tr);
      Wf[fragIdx(d, vo, 1, kk)] = (short)f2bf(-ti);
    }
    if (d < TAPS - 1) {
      float nr = 0.f, ni = 0.f;
      const float2* prow = p + mq * 34;
#pragma unroll
      for (int s = 0; s < 32; ++s) {
        const float2 pv = prow[s + (s >> 4)];
        nr = fmaf(whre[s], pv.x, fmaf(-whim[s], pv.y, nr));
        ni = fmaf(whre[s], pv.y, fmaf(whim[s], pv.x, ni));
      }
      nr += __shfl_xor(nr, 1); ni += __shfl_xor(ni, 1);
      nr += __shfl_xor(nr, 2); ni += __shfl_xor(ni, 2);
      float2* pn = pbuf + (cur ^ 1) * 136;
      if (mq == 0) pn[mi + (mi >> 4)] = make_float2(nr, ni);
    }
    __syncthreads();
    cur ^= 1;
  }
}

// ===========================================================================
// x-tile staging: fp32 -> bf16 into xs[288][136]. No barrier inside.
// ===========================================================================
__device__ __forceinline__ void stage_x(
    const float* __restrict__ xr, const float* __restrict__ xi,
    int b, int t0, short* xs) {
  const int tid = threadIdx.x;
  for (int idx = tid; idx < 288 * 16; idx += 512) {
    const int r = idx >> 4;
    const int kq = (idx & 15) << 2;
    const int t = t0 + r - 32;
    uint32_t r01 = 0u, r23 = 0u, i01 = 0u, i23 = 0u;
    if (t >= 0) {
      const size_t g = ((size_t)b * TT + t) * 64 + kq;
      const float4 vr = *(const float4*)(xr + g);
      const float4 vi = *(const float4*)(xi + g);
      r01 = f2bf(vr.x) | (f2bf(vr.y) << 16);
      r23 = f2bf(vr.z) | (f2bf(vr.w) << 16);
      i01 = f2bf(vi.x) | (f2bf(vi.y) << 16);
      i23 = f2bf(vi.z) | (f2bf(vi.w) << 16);
    }
    *(uint2*)&xs[r * 136 + kq]      = make_uint2(r01, r23);
    *(uint2*)&xs[r * 136 + 64 + kq] = make_uint2(i01, i23);
  }
}

// ===========================================================================
// Conv GEMM main. 256 blocks x 512 thr (8 waves, 2/SIMD).
// Wave w: wr = w&3 owns rows wr*64..+63 (mi=4, nt=4); kq2 = w>>2 owns
// ks in {kq2*2, kq2*2+1} (K-split; pair-reduced via LDS at the end).
// B-fragments staged per-tap in LDS (16KB, double-buffered): reg-staged
// global->VGPR early (hides L2 latency under MFMA), ds_write late.
// Tap order skewed by block to decorrelate L2 line requests.
// ===========================================================================
__device__ __forceinline__ void conv_main(
    const short* __restrict__ Wf, float* __restrict__ out,
    int b, int t0, int dskew, unsigned char* smemraw) {
  short* xs = (short*)smemraw;                   // [288][136] = 78336 B
  short* bt = (short*)(smemraw + 78336);         // [2][8192] shorts = 32768 B
  const int tid = threadIdx.x;
  const int w = tid >> 6;
  const int lane = tid & 63;
  const int wr = w & 3;          // row group 0..3
  const int kq2 = w >> 2;        // ks half 0..1
  const int lm = lane & 15;
  const int kc8 = (lane >> 4) << 3;

  // ---- B prologue: stage tap dskew into bt[0] (2 chunks of 1KB per wave)
  {
    const short* g0 = Wf + (size_t)dskew * 8192 + (w * 2) * 512 + lane * 8;
    const short8 s0 = *(const short8*)g0;
    const short8 s1 = *(const short8*)(g0 + 512);
    short* l0 = bt + (w * 2) * 512 + lane * 8;
    *(short8*)l0 = s0;
    *(short8*)(l0 + 512) = s1;
  }
  __syncthreads();   // xs staged (pre-gbar or just now) + bt[0] ready

  f32x4 acc[4][4];
#pragma unroll
  for (int mi = 0; mi < 4; ++mi)
#pragma unroll
    for (int nt = 0; nt < 4; ++nt) acc[mi][nt] = (f32x4){0.f, 0.f, 0.f, 0.f};

  short8 stg0, stg1;
  int cur = 0;
#pragma unroll 1
  for (int i = 0; i < TAPS; ++i) {
    const int d = (i + dskew) & 31;
    // issue next-tap global loads EARLY (latency hides under MFMA below)
    if (i < TAPS - 1) {
      const int dn = (d + 1) & 31;
      const short* g0 = Wf + (size_t)dn * 8192 + (w * 2) * 512 + lane * 8;
      stg0 = *(const short8*)g0;
      stg1 = *(const short8*)(g0 + 512);
    }
    // compute tap d from bt[cur]
    const short* bb = bt + cur * 8192;
    const int rb = 32 - d + wr * 64 + lm;
#pragma unroll
    for (int k2 = 0; k2 < 2; ++k2) {
      const int ks = kq2 * 2 + k2;
      const int col = (ks >> 1) * 64 + (ks & 1) * 32 + kc8;
      short8 bq[4], aq[4];
#pragma unroll
      for (int nt = 0; nt < 4; ++nt)
        bq[nt] = *(const short8*)(bb + (ks * 4 + nt) * 512 + lane * 8);
#pragma unroll
      for (int mi = 0; mi < 4; ++mi)
        aq[mi] = *(const short8*)&xs[(rb + mi * 16) * 136 + col];
#pragma unroll
      for (int mi = 0; mi < 4; ++mi)
#pragma unroll
        for (int nt = 0; nt < 4; ++nt)
          acc[mi][nt] = __builtin_amdgcn_mfma_f32_16x16x32_bf16(
              aq[mi], bq[nt], acc[mi][nt], 0, 0, 0);
    }
    // write staged regs into the other buffer (late)
    if (i < TAPS - 1) {
      short* l0 = bt + (cur ^ 1) * 8192 + (w * 2) * 512 + lane * 8;
      *(short8*)l0 = stg0;
      *(short8*)(l0 + 512) = stg1;
    }
    __syncthreads();   // bt[cur^1] ready; everyone done reading bt[cur]
    cur ^= 1;
  }

  // ---- ks-pair reduction (kq2=1 partials -> LDS -> kq2=0 adds & stores)
  // xs/bt dead after the final barrier above; reuse smem base.
  float* fred = (float*)smemraw;   // [4][64][65] floats = 66560 B
  if (kq2 == 1) {
#pragma unroll
    for (int mi = 0; mi < 4; ++mi)
#pragma unroll
      for (int nt = 0; nt < 4; ++nt)
#pragma unroll
        for (int rg = 0; rg < 4; ++rg) {
          const int mloc = ((lane >> 4) << 2) + rg + mi * 16;
          fred[wr * 4160 + mloc * 65 + nt * 16 + lm] = acc[mi][nt][rg];
        }
  }
  __syncthreads();
  if (kq2 == 0) {
    const int mrow = wr * 64 + ((lane >> 4) << 2);
#pragma unroll
    for (int mi = 0; mi < 4; ++mi) {
#pragma unroll
      for (int nt = 0; nt < 4; ++nt) {
        const int o = nt * 16 + lm;
        float* p = out + ((size_t)b * TT + t0 + mrow + mi * 16) * 64 + o;
#pragma unroll
        for (int rg = 0; rg < 4; ++rg) {
          const int mloc = ((lane >> 4) << 2) + rg + mi * 16;
          p[(size_t)rg * 64] =
              acc[mi][nt][rg] + fred[wr * 4160 + mloc * 65 + o];
        }
      }
    }
  }
}

// ===========================================================================
// The fused kernel: 256 blocks x 512 threads, ONE grid barrier.
//   blocks 0..63:  tap chain -> Wf            | blocks 64..255: pre-stage x
//   gbar
//   blocks 0..63:  stage x (late)             | all: conv_main
// 111104 B LDS -> 1 block/CU -> all 256 blocks co-resident -> gbar safe.
// ===========================================================================
__global__ __launch_bounds__(512, 2) void k_all(
    const float* __restrict__ xr, const float* __restrict__ xi,
    const float* __restrict__ wir, const float* __restrict__ wii,
    const float* __restrict__ whr, const float* __restrict__ whi,
    const float* __restrict__ wor, const float* __restrict__ woi,
    short* __restrict__ Wfr, float* __restrict__ out) {
  __shared__ __align__(16) unsigned char smem[111104];
  const int blk = blockIdx.x;
  const int NB = (int)gridDim.x;
  const int b = blk & 15;
  const int t0 = (blk >> 4) * 256;

  if (blk < 64)
    chain_dev(wir, wii, whr, whi, wor, woi, Wfr, blk, smem);
  else
    stage_x(xr, xi, b, t0, (short*)smem);   // overlap with chain phase

  gbar(NB);

  if (blk < 64)
    stage_x(xr, xi, b, t0, (short*)smem);   // chain blocks stage late

  conv_main(Wfr, out, b, t0, blk & 31, smem);
}

// ---------------------------------------------------------------------------
// FALLBACK (R8, proven 596 us): single fused truncated-scan kernel.
// Used only if ws_size < 512 KB.
// ---------------------------------------------------------------------------
__global__ __launch_bounds__(256) void k_fused(
    const float* __restrict__ xr, const float* __restrict__ xi,
    const float* __restrict__ wir, const float* __restrict__ wii,
    const float* __restrict__ whr, const float* __restrict__ whi,
    const float* __restrict__ wor, const float* __restrict__ woi,
    float* __restrict__ out) {
  __shared__ __align__(16) unsigned char smem[63488];
  uint32_t* xpl  = (uint32_t*)smem;
  uint32_t* wiq  = (uint32_t*)(smem + 49152);
  uint32_t* xtq  = (uint32_t*)(smem + 57344);
  float2*   part = (float2*)(smem + 49152);
  float2*   hbuf = (float2*)(smem + 59392);
  uint32_t* woA  = (uint32_t*)smem;
  const int tid = threadIdx.x;
  const int c = blockIdx.x >> 4;
  const int b = blockIdx.x & 15;
  const int t0 = c * LCH - WARM;

  const int ho = tid & 31;
  const int tg = tid >> 5;
  float accr[4][12], acci[4][12];
#pragma unroll
  for (int a = 0; a < 4; ++a)
#pragma unroll
    for (int t = 0; t < 12; ++t) { accr[a][t] = 0.f; acci[a][t] = 0.f; }

#pragma unroll 1
  for (int q = 0; q < 4; ++q) {
    if (q) __syncthreads();
    for (int idx = tid; idx < 16 * HH; idx += 256) {
      const int dd = idx & 15, h = idx >> 4;
      const int g = h * DIN + q * 16 + dd;
      wiq[dd * 128 + h] = pack_bf(wir[g], wii[g]);
    }
    for (int idx = tid; idx < 16 * SS; idx += 256) {
      const int dd = idx & 15, s = idx >> 4;
      const int t = t0 + s;
      uint32_t v = 0u;
      if (t >= 0) {
        const size_t g = ((size_t)b * TT + t) * DIN + q * 16 + dd;
        v = pack_bf(xr[g], xi[g]);
      }
      xtq[dd * 96 + s] = v;
    }
    __syncthreads();
#pragma unroll 4
    for (int dd = 0; dd < 16; ++dd) {
      const uint4 wv  = *(const uint4*)&wiq[dd * 128 + ho * 4];
      const uint4 xv0 = *(const uint4*)&xtq[dd * 96 + tg * 12];
      const uint4 xv1 = *(const uint4*)&xtq[dd * 96 + tg * 12 + 4];
      const uint4 xv2 = *(const uint4*)&xtq[dd * 96 + tg * 12 + 8];
      float wre[4], wim[4], xre[12], xim[12];
      wre[0] = bf_re(wv.x); wim[0] = bf_im(wv.x);
      wre[1] = bf_re(wv.y); wim[1] = bf_im(wv.y);
      wre[2] = bf_re(wv.z); wim[2] = bf_im(wv.z);
      wre[3] = bf_re(wv.w); wim[3] = bf_im(wv.w);
      xre[0] = bf_re(xv0.x); xim[0] = bf_im(xv0.x);
      xre[1] = bf_re(xv0.y); xim[1] = bf_im(xv0.y);
      xre[2] = bf_re(xv0.z); xim[2] = bf_im(xv0.z);
      xre[3] = bf_re(xv0.w); xim[3] = bf_im(xv0.w);
      xre[4] = bf_re(xv1.x); xim[4] = bf_im(xv1.x);
      xre[5] = bf_re(xv1.y); xim[5] = bf_im(xv1.y);
      xre[6] = bf_re(xv1.z); xim[6] = bf_im(xv1.z);
      xre[7] = bf_re(xv1.w); xim[7] = bf_im(xv1.w);
      xre[8] = bf_re(xv2.x); xim[8] = bf_im(xv2.x);
      xre[9] = bf_re(xv2.y); xim[9] = bf_im(xv2.y);
      xre[10] = bf_re(xv2.z); xim[10] = bf_im(xv2.z);
      xre[11] = bf_re(xv2.w); xim[11] = bf_im(xv2.w);
#pragma unroll
      for (int a = 0; a < 4; ++a)
#pragma unroll
        for (int t = 0; t < 12; ++t) {
          accr[a][t] = fmaf(wre[a], xre[t], accr[a][t]);
          accr[a][t] = fmaf(-wim[a], xim[t], accr[a][t]);
          acci[a][t] = fmaf(wre[a], xim[t], acci[a][t]);
          acci[a][t] = fmaf(wim[a], xre[t], acci[a][t]);
        }
    }
  }
  __syncthreads();

#pragma unroll
  for (int tt = 0; tt < 12; ++tt) {
    uint4 v;
    v.x = pack_bf(accr[0][tt], acci[0][tt]);
    v.y = pack_bf(accr[1][tt], acci[1][tt]);
    v.z = pack_bf(accr[2][tt], acci[2][tt]);
    v.w = pack_bf(accr[3][tt], acci[3][tt]);
    *(uint4*)&xpl[(tg * 12 + tt) * 128 + ho * 4] = v;
  }
  if (tid < HH) hbuf[tid] = make_float2(0.f, 0.f);

  const int p8 = tid & 7;
  const int jg = tid >> 3;
  float wr[4][16], wim_[4][16];
#pragma unroll
  for (int a = 0; a < 4; ++a)
#pragma unroll
    for (int i = 0; i < 16; i += 4) {
      const float4 vr = *(const float4*)(whr + (size_t)(jg * 4 + a) * HH + p8 * 16 + i);
      wr[a][i] = vr.x; wr[a][i + 1] = vr.y; wr[a][i + 2] = vr.z; wr[a][i + 3] = vr.w;
      const float4 vi = *(const float4*)(whi + (size_t)(jg * 4 + a) * HH + p8 * 16 + i);
      wim_[a][i] = vi.x; wim_[a][i + 1] = vi.y; wim_[a][i + 2] = vi.z; wim_[a][i + 3] = vi.w;
    }
  __syncthreads();

#pragma unroll 1
  for (int s = 0; s < SS; ++s) {
    const uint32_t u = (tid < HH) ? xpl[s * 128 + tid] : 0u;
    float sre[4] = {0.f, 0.f, 0.f, 0.f}, sim[4] = {0.f, 0.f, 0.f, 0.f};
#pragma unroll
    for (int i = 0; i < 16; ++i) {
      const float2 hv = hbuf[i * 8 + p8];
#pragma unroll
      for (int a = 0; a < 4; ++a) {
        sre[a] = fmaf(wr[a][i], hv.x, sre[a]);
        sre[a] = fmaf(-wim_[a][i], hv.y, sre[a]);
        sim[a] = fmaf(wr[a][i], hv.y, sim[a]);
        sim[a] = fmaf(wim_[a][i], hv.x, sim[a]);
      }
    }
#pragma unroll
    for (int a = 0; a < 4; ++a)
      part[(jg * 4 + a) * 10 + p8] = make_float2(sre[a], sim[a]);
    __syncthreads();
    if (tid < HH) {
      const int j = tid;
      const float4 q0 = *(const float4*)&part[j * 10];
      const float4 q1 = *(const float4*)&part[j * 10 + 2];
      const float4 q2 = *(const float4*)&part[j * 10 + 4];
      const float4 q3 = *(const float4*)&part[j * 10 + 6];
      const float R = ((q0.x + q0.z) + (q1.x + q1.z)) + ((q2.x + q2.z) + (q3.x + q3.z));
      const float I = ((q0.y + q0.w) + (q1.y + q1.w)) + ((q2.y + q2.w) + (q3.y + q3.w));
      const float hr = bf_re(u) - I;
      const float hi = bf_im(u) + R;
      hbuf[(j & 15) * 8 + (j >> 4)] = make_float2(hr, hi);
      if (s >= WARM) xpl[s * 128 + j] = pack_bf(hr, hi);
    }
    __syncthreads();
  }

  const int og = tid & 15;
  const int tg2 = tid >> 4;
  float orr[4][4];
#pragma unroll
  for (int a = 0; a < 4; ++a)
#pragma unroll
    for (int t = 0; t < 4; ++t) orr[a][t] = 0.f;
#pragma unroll 1
  for (int kp = 0; kp < 2; ++kp) {
    __syncthreads();
    for (int idx = tid; idx < DOUT * 64; idx += 256) {
      const int o = idx >> 6, hh = idx & 63;
      woA[hh * 64 + o] = pack_bf(wor[(size_t)o * HH + kp * 64 + hh],
                                 woi[(size_t)o * HH + kp * 64 + hh]);
    }
    __syncthreads();
    for (int hh = 0; hh < 64; ++hh) {
      const uint4 wv = *(const uint4*)&woA[hh * 64 + og * 4];
      float wre[4], wimv[4];
      wre[0] = bf_re(wv.x); wimv[0] = bf_im(wv.x);
      wre[1] = bf_re(wv.y); wimv[1] = bf_im(wv.y);
      wre[2] = bf_re(wv.z); wimv[2] = bf_im(wv.z);
      wre[3] = bf_re(wv.w); wimv[3] = bf_im(wv.w);
#pragma unroll
      for (int tt = 0; tt < 4; ++tt) {
        const uint32_t hu = xpl[(WARM + tg2 * 4 + tt) * 128 + kp * 64 + hh];
        const float hre = bf_re(hu), him = bf_im(hu);
#pragma unroll
        for (int a = 0; a < 4; ++a) {
          orr[a][tt] = fmaf(wre[a], hre, orr[a][tt]);
          orr[a][tt] = fmaf(-wimv[a], him, orr[a][tt]);
        }
      }
    }
  }
#pragma unroll
  for (int tt = 0; tt < 4; ++tt) {
    float* po = out + ((size_t)b * TT + (size_t)c * LCH + tg2 * 4 + tt) * DOUT + og * 4;
    *(float4*)po = make_float4(orr[0][tt], orr[1][tt], orr[2][tt], orr[3][tt]);
  }
}

// ---------------------------------------------------------------------------
extern "C" void kernel_launch(void* const* d_in, const int* in_sizes, int n_in,
                              void* d_out, int out_size, void* d_ws, size_t ws_size,
                              hipStream_t stream) {
  const float* xr  = (const float*)d_in[0];
  const float* xi  = (const float*)d_in[1];
  const float* wir = (const float*)d_in[2];
  const float* wii = (const float*)d_in[3];
  const float* whr = (const float*)d_in[4];
  const float* whi = (const float*)d_in[5];
  const float* wor = (const float*)d_in[6];
  const float* woi = (const float*)d_in[7];
  float* out = (float*)d_out;
  (void)in_sizes; (void)n_in; (void)out_size;

  const size_t NEED = 524288;   // Wf fragment buffer: 256K shorts = 512 KB
  if (ws_size >= NEED) {
    k_all<<<256, 512, 0, stream>>>(xr, xi, wir, wii, whr, whi, wor, woi,
                                   (short*)d_ws, out);
  } else {
    k_fused<<<(TT / LCH) * BB, 256, 0, stream>>>(
        xr, xi, wir, wii, whr, whi, wor, woi, out);
  }
}

// Round 7
// 171.806 us; speedup vs baseline: 3.5283x; 1.0305x over previous
//
#include <hip/hip_runtime.h>
#include <stdint.h>

// Problem constants
#define BB   16
#define TT   4096
#define DIN  64
#define DOUT 64
#define HH   128
#define LCH  64
#define WARM 32
#define SS   96
#define TAPS 32   // validated: R8's 32-step truncation gave absmax == exact path

// HARD-WON FACTS (rounds 0-15):
//  * d_out = 4,194,304 float32 (16 MB): REAL PART only, flat (b*4096+t)*64+o.
//  * 32-tap history truncation is numerically free (absmax 0.0625 == exact).
//  * R9: 11-kernel chain = 276us (conv standalone 75us). R10: cg sync 510us.
//  * R11: gbar x6 = 200us. R12: depth-1 chain + 1 gbar = 123us.
//  * R14: tap-split conv = 112us. R15: B staged in LDS = 110us (NO change).
//  * Conv ~75-90us is INVARIANT to load:MFMA ratio, B-from-L2 vs B-from-LDS,
//    and tap skew -> not B-side. The invariant is the A-side xs read:
//    ds_read_b128, 16 lanes reading consecutive ROWS at same col. Any 16B-
//    aligned row stride is = 0 mod 4 words -> banks 4k+p -> 8-WAY CONFLICT
//    (2.94x, m136). Padding cannot fix it (alignment); T2 XOR-swizzle can.
//  * This round: (1) xs swizzle byte ^= ((row&7)<<4), stride 128 shorts ->
//    conflict-free aq; (2) split chain/conv into 2 kernels (no gbar) so
//    rocprof decomposes the time per phase.

typedef __attribute__((ext_vector_type(8))) short short8;   // 8 bf16 (4 VGPR)
typedef __attribute__((ext_vector_type(4))) float f32x4;

// ---------- bf16 pack helpers (RNE) ----------
__device__ __forceinline__ uint32_t f2bf(float f) {
  uint32_t x = __float_as_uint(f);
  return (x + 0x7FFFu + ((x >> 16) & 1u)) >> 16;
}
__device__ __forceinline__ uint32_t pack_bf(float re, float im) {
  return f2bf(re) | (f2bf(im) << 16);
}
__device__ __forceinline__ float bf_re(uint32_t u) { return __uint_as_float(u << 16); }
__device__ __forceinline__ float bf_im(uint32_t u) { return __uint_as_float(u & 0xFFFF0000u); }

// fragment-major index for W: B-operand of mfma_f32_16x16x32_bf16
// lane = (k32>>3)*16 + (o&15), j = k32&7; frag id = d*16 + ks*4 + nt
__device__ __forceinline__ int fragIdx(int d, int o, int part, int kk) {
  const int ks = part * 2 + (kk >> 5);
  const int k32 = kk & 31;
  const int nt = o >> 4;
  const int lane = ((k32 >> 3) << 4) | (o & 15);
  return (((d * 16 + ks * 4 + nt) * 64) + lane) * 8 + (k32 & 7);
}

// ===========================================================================
// Kernel 1: per-column tap chain (proven R12). Block kk (0..63):
//   p_0 = Wi[:,kk]; p_{d+1} = Wh p_d; V_d[:,kk] = i^d (Wo p_d) -> Wf frags.
// ===========================================================================
__global__ __launch_bounds__(512, 1) void k_chain(
    const float* __restrict__ wir, const float* __restrict__ wii,
    const float* __restrict__ whr, const float* __restrict__ whi,
    const float* __restrict__ wor, const float* __restrict__ woi,
    short* __restrict__ Wf) {
  __shared__ __align__(16) unsigned char smemraw[71296];
  float2* pbuf = (float2*)smemraw;            // [2][136]  (2176 B)
  float2* wo   = (float2*)(smemraw + 2176);   // [64][135] padded (69120 B)
  const int kk = blockIdx.x;
  const int tid = threadIdx.x;
  const int mi = tid >> 2, mq = tid & 3;      // matvec role
  const int vo = tid >> 3, vg = tid & 7;      // V role

  float whre[32], whim[32];
  {
    const float* pr = whr + mi * 128 + mq * 32;
    const float* pi_ = whi + mi * 128 + mq * 32;
#pragma unroll
    for (int s = 0; s < 32; s += 4) {
      const float4 a = *(const float4*)(pr + s);
      whre[s] = a.x; whre[s + 1] = a.y; whre[s + 2] = a.z; whre[s + 3] = a.w;
      const float4 b = *(const float4*)(pi_ + s);
      whim[s] = b.x; whim[s + 1] = b.y; whim[s + 2] = b.z; whim[s + 3] = b.w;
    }
  }
  for (int idx = tid; idx < 8192; idx += 512) {
    const int o = idx >> 7, h = idx & 127;
    wo[o * 135 + h + (h >> 4)] = make_float2(wor[o * 128 + h], woi[o * 128 + h]);
  }
  if (tid < 128)
    pbuf[tid + (tid >> 4)] = make_float2(wir[tid * 64 + kk], wii[tid * 64 + kk]);
  __syncthreads();

  int cur = 0;
#pragma unroll 1
  for (int d = 0; d < TAPS; ++d) {
    const float2* p = pbuf + cur * 136;
    float vr = 0.f, vi = 0.f;
    {
      const float2* wrow = wo + vo * 135 + vg * 17;
      const float2* prow = p + vg * 17;
#pragma unroll
      for (int s = 0; s < 16; ++s) {
        const float2 a = wrow[s];
        const float2 pv = prow[s];
        vr = fmaf(a.x, pv.x, fmaf(-a.y, pv.y, vr));
        vi = fmaf(a.x, pv.y, fmaf(a.y, pv.x, vi));
      }
    }
    vr += __shfl_xor(vr, 1); vi += __shfl_xor(vi, 1);
    vr += __shfl_xor(vr, 2); vi += __shfl_xor(vi, 2);
    vr += __shfl_xor(vr, 4); vi += __shfl_xor(vi, 4);
    if (vg == 0) {
      float tr, ti;
      switch (d & 3) {                 // multiply by i^d
        case 0: tr = vr;  ti = vi;  break;
        case 1: tr = -vi; ti = vr;  break;
        case 2: tr = -vr; ti = -vi; break;
        default: tr = vi; ti = -vr; break;
      }
      Wf[fragIdx(d, vo, 0, kk)] = (short)f2bf(tr);    // Re(V)
      Wf[fragIdx(d, vo, 1, kk)] = (short)f2bf(-ti);   // -Im(V)
    }
    if (d < TAPS - 1) {
      float nr = 0.f, ni = 0.f;
      const float2* prow = p + mq * 34;
#pragma unroll
      for (int s = 0; s < 32; ++s) {
        const float2 pv = prow[s + (s >> 4)];
        nr = fmaf(whre[s], pv.x, fmaf(-whim[s], pv.y, nr));
        ni = fmaf(whre[s], pv.y, fmaf(whim[s], pv.x, ni));
      }
      nr += __shfl_xor(nr, 1); ni += __shfl_xor(ni, 1);
      nr += __shfl_xor(nr, 2); ni += __shfl_xor(ni, 2);
      float2* pn = pbuf + (cur ^ 1) * 136;
      if (mq == 0) pn[mi + (mi >> 4)] = make_float2(nr, ni);
    }
    __syncthreads();
    cur ^= 1;
  }
}

// ===========================================================================
// Kernel 2: conv GEMM. 256 blocks x 512 thr (8 waves, 2/SIMD).
// Wave w: wr = w>>1 rows wr*64..+63; kh = w&1 taps kh*16..+16; nt=4.
// xs is XOR-SWIZZLED (T2): row stride 128 shorts (256 B), element at
// (row, col_short) lives at byte row*256 + ((col*2) ^ ((row&7)<<4)).
// 8 consecutive rows -> 8 distinct 16B slots -> conflict-free ds_read_b128.
// Register double-buffered FETCH (R14 structure). kh pair-reduce via LDS.
// ===========================================================================
__global__ __launch_bounds__(512, 1) void k_conv2(
    const float* __restrict__ xr, const float* __restrict__ xi,
    const short* __restrict__ Wf, float* __restrict__ out) {
  __shared__ __align__(16) unsigned char smem[73728];   // xs 288*256B
  char* xs = (char*)smem;
  const int tid = threadIdx.x;
  const int b = blockIdx.x & 15;
  const int t0 = (blockIdx.x >> 4) * 256;

  // ---- stage x tile (fp32 -> bf16), swizzled ----
  for (int idx = tid; idx < 288 * 16; idx += 512) {
    const int r = idx >> 4;
    const int kq = (idx & 15) << 2;          // short col 0,4,..,60
    const int sw = (r & 7) << 4;
    const int t = t0 + r - 32;
    uint32_t r01 = 0u, r23 = 0u, i01 = 0u, i23 = 0u;
    if (t >= 0) {
      const size_t g = ((size_t)b * TT + t) * 64 + kq;
      const float4 vr = *(const float4*)(xr + g);
      const float4 vi = *(const float4*)(xi + g);
      r01 = f2bf(vr.x) | (f2bf(vr.y) << 16);
      r23 = f2bf(vr.z) | (f2bf(vr.w) << 16);
      i01 = f2bf(vi.x) | (f2bf(vi.y) << 16);
      i23 = f2bf(vi.z) | (f2bf(vi.w) << 16);
    }
    char* rowp = xs + r * 256;
    *(uint2*)(rowp + ((kq * 2) ^ sw))         = make_uint2(r01, r23);
    *(uint2*)(rowp + ((128 + kq * 2) ^ sw))   = make_uint2(i01, i23);
  }
  __syncthreads();

  const int w = tid >> 6;
  const int lane = tid & 63;
  const int wr = w >> 1;        // row group 0..3
  const int kh = w & 1;         // tap half 0..1
  const int lm = lane & 15;
  const int kc8 = (lane >> 4) << 3;

  f32x4 acc[4][4];
#pragma unroll
  for (int mi = 0; mi < 4; ++mi)
#pragma unroll
    for (int nt = 0; nt < 4; ++nt) acc[mi][nt] = (f32x4){0.f, 0.f, 0.f, 0.f};

  // fetch helper: it in [0,64): d = kh*16 + (it>>2), ks = it&3
  short8 aqA[4], bqA[4], aqB[4], bqB[4];
#define FETCH(IT, AQ, BQ)                                                     \
  do {                                                                        \
    const int d_ = kh * 16 + ((IT) >> 2);                                     \
    const int ks_ = (IT) & 3;                                                 \
    const int rb_ = 32 - d_ + wr * 64 + lm;                                   \
    const int colb_ = ((ks_ >> 1) * 64 + (ks_ & 1) * 32 + kc8) * 2;           \
    _Pragma("unroll")                                                         \
    for (int nt_ = 0; nt_ < 4; ++nt_)                                         \
      BQ[nt_] = *(const short8*)(Wf +                                         \
          (((d_ * 16 + ks_ * 4 + nt_) * 64 + lane) << 3));                    \
    _Pragma("unroll")                                                         \
    for (int mi_ = 0; mi_ < 4; ++mi_) {                                       \
      const int r_ = rb_ + mi_ * 16;                                          \
      AQ[mi_] = *(const short8*)(xs + r_ * 256 +                              \
                                 (colb_ ^ ((r_ & 7) << 4)));                  \
    }                                                                         \
  } while (0)

#define MFMAGRP(AQ, BQ)                                                       \
  do {                                                                        \
    _Pragma("unroll")                                                         \
    for (int mi_ = 0; mi_ < 4; ++mi_)                                         \
      _Pragma("unroll")                                                       \
      for (int nt_ = 0; nt_ < 4; ++nt_)                                       \
        acc[mi_][nt_] = __builtin_amdgcn_mfma_f32_16x16x32_bf16(              \
            AQ[mi_], BQ[nt_], acc[mi_][nt_], 0, 0, 0);                        \
  } while (0)

  FETCH(0, aqA, bqA);
#pragma unroll 1
  for (int it = 0; it < 62; it += 2) {
    FETCH(it + 1, aqB, bqB);
    MFMAGRP(aqA, bqA);
    FETCH(it + 2, aqA, bqA);
    MFMAGRP(aqB, bqB);
  }
  FETCH(63, aqB, bqB);
  MFMAGRP(aqA, bqA);
  MFMAGRP(aqB, bqB);
#undef FETCH
#undef MFMAGRP

  // ---- tap-half pair reduction (kh=1 -> LDS -> kh=0 adds & stores) ----
  __syncthreads();                 // all waves done reading xs
  float* fred = (float*)smem;      // [4][64][65] floats = 66560 B <= 73728
  if (kh == 1) {
#pragma unroll
    for (int mi = 0; mi < 4; ++mi)
#pragma unroll
      for (int nt = 0; nt < 4; ++nt)
#pragma unroll
        for (int rg = 0; rg < 4; ++rg) {
          const int mloc = ((lane >> 4) << 2) + rg + mi * 16;
          fred[wr * 4160 + mloc * 65 + nt * 16 + lm] = acc[mi][nt][rg];
        }
  }
  __syncthreads();
  if (kh == 0) {
    const int mrow = wr * 64 + ((lane >> 4) << 2);
#pragma unroll
    for (int mi = 0; mi < 4; ++mi) {
#pragma unroll
      for (int nt = 0; nt < 4; ++nt) {
        const int o = nt * 16 + lm;
        float* p = out + ((size_t)b * TT + t0 + mrow + mi * 16) * 64 + o;
#pragma unroll
        for (int rg = 0; rg < 4; ++rg) {
          const int mloc = ((lane >> 4) << 2) + rg + mi * 16;
          p[(size_t)rg * 64] =
              acc[mi][nt][rg] + fred[wr * 4160 + mloc * 65 + o];
        }
      }
    }
  }
}

// ---------------------------------------------------------------------------
// FALLBACK (R8, proven 596 us): single fused truncated-scan kernel.
// Used only if ws_size < 512 KB.
// ---------------------------------------------------------------------------
__global__ __launch_bounds__(256) void k_fused(
    const float* __restrict__ xr, const float* __restrict__ xi,
    const float* __restrict__ wir, const float* __restrict__ wii,
    const float* __restrict__ whr, const float* __restrict__ whi,
    const float* __restrict__ wor, const float* __restrict__ woi,
    float* __restrict__ out) {
  __shared__ __align__(16) unsigned char smem[63488];
  uint32_t* xpl  = (uint32_t*)smem;
  uint32_t* wiq  = (uint32_t*)(smem + 49152);
  uint32_t* xtq  = (uint32_t*)(smem + 57344);
  float2*   part = (float2*)(smem + 49152);
  float2*   hbuf = (float2*)(smem + 59392);
  uint32_t* woA  = (uint32_t*)smem;
  const int tid = threadIdx.x;
  const int c = blockIdx.x >> 4;
  const int b = blockIdx.x & 15;
  const int t0 = c * LCH - WARM;

  const int ho = tid & 31;
  const int tg = tid >> 5;
  float accr[4][12], acci[4][12];
#pragma unroll
  for (int a = 0; a < 4; ++a)
#pragma unroll
    for (int t = 0; t < 12; ++t) { accr[a][t] = 0.f; acci[a][t] = 0.f; }

#pragma unroll 1
  for (int q = 0; q < 4; ++q) {
    if (q) __syncthreads();
    for (int idx = tid; idx < 16 * HH; idx += 256) {
      const int dd = idx & 15, h = idx >> 4;
      const int g = h * DIN + q * 16 + dd;
      wiq[dd * 128 + h] = pack_bf(wir[g], wii[g]);
    }
    for (int idx = tid; idx < 16 * SS; idx += 256) {
      const int dd = idx & 15, s = idx >> 4;
      const int t = t0 + s;
      uint32_t v = 0u;
      if (t >= 0) {
        const size_t g = ((size_t)b * TT + t) * DIN + q * 16 + dd;
        v = pack_bf(xr[g], xi[g]);
      }
      xtq[dd * 96 + s] = v;
    }
    __syncthreads();
#pragma unroll 4
    for (int dd = 0; dd < 16; ++dd) {
      const uint4 wv  = *(const uint4*)&wiq[dd * 128 + ho * 4];
      const uint4 xv0 = *(const uint4*)&xtq[dd * 96 + tg * 12];
      const uint4 xv1 = *(const uint4*)&xtq[dd * 96 + tg * 12 + 4];
      const uint4 xv2 = *(const uint4*)&xtq[dd * 96 + tg * 12 + 8];
      float wre[4], wim[4], xre[12], xim[12];
      wre[0] = bf_re(wv.x); wim[0] = bf_im(wv.x);
      wre[1] = bf_re(wv.y); wim[1] = bf_im(wv.y);
      wre[2] = bf_re(wv.z); wim[2] = bf_im(wv.z);
      wre[3] = bf_re(wv.w); wim[3] = bf_im(wv.w);
      xre[0] = bf_re(xv0.x); xim[0] = bf_im(xv0.x);
      xre[1] = bf_re(xv0.y); xim[1] = bf_im(xv0.y);
      xre[2] = bf_re(xv0.z); xim[2] = bf_im(xv0.z);
      xre[3] = bf_re(xv0.w); xim[3] = bf_im(xv0.w);
      xre[4] = bf_re(xv1.x); xim[4] = bf_im(xv1.x);
      xre[5] = bf_re(xv1.y); xim[5] = bf_im(xv1.y);
      xre[6] = bf_re(xv1.z); xim[6] = bf_im(xv1.z);
      xre[7] = bf_re(xv1.w); xim[7] = bf_im(xv1.w);
      xre[8] = bf_re(xv2.x); xim[8] = bf_im(xv2.x);
      xre[9] = bf_re(xv2.y); xim[9] = bf_im(xv2.y);
      xre[10] = bf_re(xv2.z); xim[10] = bf_im(xv2.z);
      xre[11] = bf_re(xv2.w); xim[11] = bf_im(xv2.w);
#pragma unroll
      for (int a = 0; a < 4; ++a)
#pragma unroll
        for (int t = 0; t < 12; ++t) {
          accr[a][t] = fmaf(wre[a], xre[t], accr[a][t]);
          accr[a][t] = fmaf(-wim[a], xim[t], accr[a][t]);
          acci[a][t] = fmaf(wre[a], xim[t], acci[a][t]);
          acci[a][t] = fmaf(wim[a], xre[t], acci[a][t]);
        }
    }
  }
  __syncthreads();

#pragma unroll
  for (int tt = 0; tt < 12; ++tt) {
    uint4 v;
    v.x = pack_bf(accr[0][tt], acci[0][tt]);
    v.y = pack_bf(accr[1][tt], acci[1][tt]);
    v.z = pack_bf(accr[2][tt], acci[2][tt]);
    v.w = pack_bf(accr[3][tt], acci[3][tt]);
    *(uint4*)&xpl[(tg * 12 + tt) * 128 + ho * 4] = v;
  }
  if (tid < HH) hbuf[tid] = make_float2(0.f, 0.f);

  const int p8 = tid & 7;
  const int jg = tid >> 3;
  float wr[4][16], wim_[4][16];
#pragma unroll
  for (int a = 0; a < 4; ++a)
#pragma unroll
    for (int i = 0; i < 16; i += 4) {
      const float4 vr = *(const float4*)(whr + (size_t)(jg * 4 + a) * HH + p8 * 16 + i);
      wr[a][i] = vr.x; wr[a][i + 1] = vr.y; wr[a][i + 2] = vr.z; wr[a][i + 3] = vr.w;
      const float4 vi = *(const float4*)(whi + (size_t)(jg * 4 + a) * HH + p8 * 16 + i);
      wim_[a][i] = vi.x; wim_[a][i + 1] = vi.y; wim_[a][i + 2] = vi.z; wim_[a][i + 3] = vi.w;
    }
  __syncthreads();

#pragma unroll 1
  for (int s = 0; s < SS; ++s) {
    const uint32_t u = (tid < HH) ? xpl[s * 128 + tid] : 0u;
    float sre[4] = {0.f, 0.f, 0.f, 0.f}, sim[4] = {0.f, 0.f, 0.f, 0.f};
#pragma unroll
    for (int i = 0; i < 16; ++i) {
      const float2 hv = hbuf[i * 8 + p8];
#pragma unroll
      for (int a = 0; a < 4; ++a) {
        sre[a] = fmaf(wr[a][i], hv.x, sre[a]);
        sre[a] = fmaf(-wim_[a][i], hv.y, sre[a]);
        sim[a] = fmaf(wr[a][i], hv.y, sim[a]);
        sim[a] = fmaf(wim_[a][i], hv.x, sim[a]);
      }
    }
#pragma unroll
    for (int a = 0; a < 4; ++a)
      part[(jg * 4 + a) * 10 + p8] = make_float2(sre[a], sim[a]);
    __syncthreads();
    if (tid < HH) {
      const int j = tid;
      const float4 q0 = *(const float4*)&part[j * 10];
      const float4 q1 = *(const float4*)&part[j * 10 + 2];
      const float4 q2 = *(const float4*)&part[j * 10 + 4];
      const float4 q3 = *(const float4*)&part[j * 10 + 6];
      const float R = ((q0.x + q0.z) + (q1.x + q1.z)) + ((q2.x + q2.z) + (q3.x + q3.z));
      const float I = ((q0.y + q0.w) + (q1.y + q1.w)) + ((q2.y + q2.w) + (q3.y + q3.w));
      const float hr = bf_re(u) - I;
      const float hi = bf_im(u) + R;
      hbuf[(j & 15) * 8 + (j >> 4)] = make_float2(hr, hi);
      if (s >= WARM) xpl[s * 128 + j] = pack_bf(hr, hi);
    }
    __syncthreads();
  }

  const int og = tid & 15;
  const int tg2 = tid >> 4;
  float orr[4][4];
#pragma unroll
  for (int a = 0; a < 4; ++a)
#pragma unroll
    for (int t = 0; t < 4; ++t) orr[a][t] = 0.f;
#pragma unroll 1
  for (int kp = 0; kp < 2; ++kp) {
    __syncthreads();
    for (int idx = tid; idx < DOUT * 64; idx += 256) {
      const int o = idx >> 6, hh = idx & 63;
      woA[hh * 64 + o] = pack_bf(wor[(size_t)o * HH + kp * 64 + hh],
                                 woi[(size_t)o * HH + kp * 64 + hh]);
    }
    __syncthreads();
    for (int hh = 0; hh < 64; ++hh) {
      const uint4 wv = *(const uint4*)&woA[hh * 64 + og * 4];
      float wre[4], wimv[4];
      wre[0] = bf_re(wv.x); wimv[0] = bf_im(wv.x);
      wre[1] = bf_re(wv.y); wimv[1] = bf_im(wv.y);
      wre[2] = bf_re(wv.z); wimv[2] = bf_im(wv.z);
      wre[3] = bf_re(wv.w); wimv[3] = bf_im(wv.w);
#pragma unroll
      for (int tt = 0; tt < 4; ++tt) {
        const uint32_t hu = xpl[(WARM + tg2 * 4 + tt) * 128 + kp * 64 + hh];
        const float hre = bf_re(hu), him = bf_im(hu);
#pragma unroll
        for (int a = 0; a < 4; ++a) {
          orr[a][tt] = fmaf(wre[a], hre, orr[a][tt]);
          orr[a][tt] = fmaf(-wimv[a], him, orr[a][tt]);
        }
      }
    }
  }
#pragma unroll
  for (int tt = 0; tt < 4; ++tt) {
    float* po = out + ((size_t)b * TT + (size_t)c * LCH + tg2 * 4 + tt) * DOUT + og * 4;
    *(float4*)po = make_float4(orr[0][tt], orr[1][tt], orr[2][tt], orr[3][tt]);
  }
}

// ---------------------------------------------------------------------------
extern "C" void kernel_launch(void* const* d_in, const int* in_sizes, int n_in,
                              void* d_out, int out_size, void* d_ws, size_t ws_size,
                              hipStream_t stream) {
  const float* xr  = (const float*)d_in[0];
  const float* xi  = (const float*)d_in[1];
  const float* wir = (const float*)d_in[2];
  const float* wii = (const float*)d_in[3];
  const float* whr = (const float*)d_in[4];
  const float* whi = (const float*)d_in[5];
  const float* wor = (const float*)d_in[6];
  const float* woi = (const float*)d_in[7];
  float* out = (float*)d_out;
  (void)in_sizes; (void)n_in; (void)out_size;

  const size_t NEED = 524288;   // Wf fragment buffer: 256K shorts = 512 KB
  if (ws_size >= NEED) {
    short* Wfr = (short*)d_ws;
    k_chain<<<64, 512, 0, stream>>>(wir, wii, whr, whi, wor, woi, Wfr);
    k_conv2<<<256, 512, 0, stream>>>(xr, xi, Wfr, out);
  } else {
    k_fused<<<(TT / LCH) * BB, 256, 0, stream>>>(
        xr, xi, wir, wii, whr, whi, wor, woi, out);
  }
}